// Round 1
// baseline (921.109 us; speedup 1.0000x reference)
//
#include <hip/hip_runtime.h>
#include <math.h>

// Problem constants (B=1, H=4, N=2048, D=64, M=256)
#define BH   4
#define SEQ  2048
#define DH   64
#define NF   256
#define ROWS (BH*SEQ)            // 8192
#define DN    0.35355339059327373f   // 64^-0.25
#define DIAGC 0.0625f                // 0.5*DN*DN
#define RATIO 0.0625f                // 1/sqrt(256)
#define EPSF  1e-4f

#define CHUNK  128
#define NCHUNK 16                // SEQ/CHUNK

// ---------------- q features: dash + rowmax + exp, fully fused ----------------
__global__ __launch_bounds__(256) void kq_feat(const float* __restrict__ q,
                                               const float* __restrict__ P,
                                               float* __restrict__ qf) {
  const int row = blockIdx.x;    // bh*SEQ + n
  const int m = threadIdx.x;     // 0..255
  __shared__ float sq[DH];
  __shared__ float red[256];
  if (m < DH) sq[m] = q[(size_t)row*DH + m];
  __syncthreads();
  float acc = 0.f, ss = 0.f;
  const float* Pm = P + m*DH;
#pragma unroll
  for (int d = 0; d < DH; ++d) { float x = sq[d]; acc += x*Pm[d]; ss += x*x; }
  float qd = DN * acc;
  red[m] = qd;
  __syncthreads();
  for (int s = 128; s > 0; s >>= 1) {
    if (m < s) red[m] = fmaxf(red[m], red[m+s]);
    __syncthreads();
  }
  float rmax = red[0];
  float diag = ss * DIAGC;
  qf[(size_t)row*NF + m] = RATIO * (expf(qd - diag - rmax) + EPSF);
}

// ---------------- k dash + per-row diag + per-row(block) max ----------------
__global__ __launch_bounds__(256) void kk_dash(const float* __restrict__ k,
                                               const float* __restrict__ P,
                                               float* __restrict__ kd,
                                               float* __restrict__ diagk,
                                               float* __restrict__ bmax) {
  const int row = blockIdx.x;
  const int m = threadIdx.x;
  __shared__ float sk[DH];
  __shared__ float red[256];
  if (m < DH) sk[m] = k[(size_t)row*DH + m];
  __syncthreads();
  float acc = 0.f, ss = 0.f;
  const float* Pm = P + m*DH;
#pragma unroll
  for (int d = 0; d < DH; ++d) { float x = sk[d]; acc += x*Pm[d]; ss += x*x; }
  float kdv = DN * acc;
  kd[(size_t)row*NF + m] = kdv;
  red[m] = kdv;
  __syncthreads();
  for (int s = 128; s > 0; s >>= 1) {
    if (m < s) red[m] = fmaxf(red[m], red[m+s]);
    __syncthreads();
  }
  if (m == 0) { bmax[row] = red[0]; diagk[row] = ss * DIAGC; }
}

// ---------------- global max over all k_dash (deterministic) ----------------
__global__ __launch_bounds__(256) void kk_gmax(const float* __restrict__ bmax,
                                               float* __restrict__ gmaxp) {
  __shared__ float red[256];
  const int t = threadIdx.x;
  float mx = -3.4e38f;
  for (int i = t; i < ROWS; i += 256) mx = fmaxf(mx, bmax[i]);
  red[t] = mx;
  __syncthreads();
  for (int s = 128; s > 0; s >>= 1) {
    if (t < s) red[t] = fmaxf(red[t], red[t+s]);
    __syncthreads();
  }
  if (t == 0) gmaxp[0] = red[0];
}

// ---------------- k_feat (in-place over k_dash) + chunk partial sums ----------------
__global__ __launch_bounds__(256) void kk_feat(float* __restrict__ kdkf,
                                               const float* __restrict__ diagk,
                                               const float* __restrict__ gmaxp,
                                               float* __restrict__ csum) {
  const int bh = blockIdx.x >> 4;
  const int ch = blockIdx.x & 15;
  const int m = threadIdx.x;
  const float g = gmaxp[0];
  const int r0 = bh*SEQ + ch*CHUNK;
  float run = 0.f;
  for (int r = 0; r < CHUNK; ++r) {
    const int row = r0 + r;
    const size_t idx = (size_t)row*NF + m;
    float kf = RATIO * (expf(kdkf[idx] - diagk[row] - g) + EPSF);
    run += kf;
    kdkf[idx] = kf;
  }
  csum[(size_t)(bh*NCHUNK + ch)*NF + m] = run;
}

// ---------------- q' = q_feat / cumsum(k_feat)  (in-place over q_feat) ----------------
__global__ __launch_bounds__(256) void kq_prime(float* __restrict__ qf,
                                                const float* __restrict__ kf,
                                                const float* __restrict__ csum) {
  const int bh = blockIdx.x >> 4;
  const int ch = blockIdx.x & 15;
  const int m = threadIdx.x;
  float run = 0.f;
  for (int c = 0; c < ch; ++c) run += csum[(size_t)(bh*NCHUNK + c)*NF + m];
  const int r0 = bh*SEQ + ch*CHUNK;
  for (int r = 0; r < CHUNK; ++r) {
    const size_t idx = (size_t)(r0 + r)*NF + m;
    run += kf[idx];
    qf[idx] = qf[idx] / run;
  }
}

// ---------------- causal quadratic attention: out = (q' kfT masked) v ----------------
#define RB 32
#define CBL 64
__global__ __launch_bounds__(256) void k_attn(const float* __restrict__ qp,
                                              const float* __restrict__ kf,
                                              const float* __restrict__ v,
                                              float* __restrict__ out) {
  const int rb = blockIdx.x;     // 0..63
  const int bh = blockIdx.y;     // 0..3
  const int row0 = rb * RB;
  const int tid = threadIdx.x;
  const int ti = tid >> 5;       // 0..7 -> 4-row group
  const int i0 = ti * 4;
  const int jj = tid & 31;

  __shared__ float Qs[RB][NF + 1];    // 32 x 257  (~32.9 KB)
  __shared__ float Ks[CBL][64 + 1];   // 64 x 65   (~16.6 KB)
  __shared__ float Ss[RB][CBL + 1];   // 32 x 65   (~8.3 KB)

  // load Q' tile: 32x256 floats, coalesced float4
  {
    const float* qb = qp + (size_t)(bh*SEQ + row0)*NF;
    for (int t = 0; t < 8; ++t) {
      int flat = (t*256 + tid) * 4;
      int i  = flat >> 8;
      int kk = flat & 255;
      float4 val = *reinterpret_cast<const float4*>(qb + flat);
      Qs[i][kk]   = val.x;
      Qs[i][kk+1] = val.y;
      Qs[i][kk+2] = val.z;
      Qs[i][kk+3] = val.w;
    }
  }

  float o[4][2] = {};
  const int cbmax = rb >> 1;
  const float* kb_base = kf + (size_t)bh*SEQ*NF;
  const float* vb_base = v  + (size_t)bh*SEQ*DH;

  for (int cb = 0; cb <= cbmax; ++cb) {
    float s[4][2] = {};
    for (int kc = 0; kc < 4; ++kc) {
      __syncthreads();   // protect Ks (prev use) / Qs initial load
      // load Ks chunk: 64 rows x 64 features, coalesced float4
      for (int t = 0; t < 4; ++t) {
        int flat = (t*256 + tid) * 4;   // 0..4095
        int j  = flat >> 6;
        int kk = flat & 63;
        float4 val = *reinterpret_cast<const float4*>(
            kb_base + (size_t)(cb*CBL + j)*NF + kc*64 + kk);
        Ks[j][kk]   = val.x;
        Ks[j][kk+1] = val.y;
        Ks[j][kk+2] = val.z;
        Ks[j][kk+3] = val.w;
      }
      __syncthreads();
      const int kb0 = kc*64;
      for (int kk = 0; kk < 64; ++kk) {
        float k0 = Ks[jj][kk];
        float k1 = Ks[jj+32][kk];
#pragma unroll
        for (int r = 0; r < 4; ++r) {
          float qv = Qs[i0+r][kb0+kk];
          s[r][0] += qv*k0;
          s[r][1] += qv*k1;
        }
      }
    }
    __syncthreads();
    // causal mask (only the diagonal block is partial) + stage S in LDS
    const bool dia = (cb == cbmax);
#pragma unroll
    for (int r = 0; r < 4; ++r) {
      int ig  = row0 + i0 + r;
      int jg0 = cb*CBL + jj;
      Ss[i0+r][jj]    = (!dia || jg0      <= ig) ? s[r][0] : 0.f;
      Ss[i0+r][jj+32] = (!dia || jg0 + 32 <= ig) ? s[r][1] : 0.f;
    }
    __syncthreads();
    // PV: O += S * V   (V read from global, L2-resident)
    const float* vb = vb_base + (size_t)cb*CBL*DH;
    for (int j2 = 0; j2 < CBL; ++j2) {
      float va = vb[(size_t)j2*DH + jj];
      float vc = vb[(size_t)j2*DH + jj + 32];
#pragma unroll
      for (int r = 0; r < 4; ++r) {
        float sv = Ss[i0+r][j2];
        o[r][0] += sv*va;
        o[r][1] += sv*vc;
      }
    }
  }

  float* ob = out + (size_t)(bh*SEQ + row0)*DH;
#pragma unroll
  for (int r = 0; r < 4; ++r) {
    ob[(size_t)(i0+r)*DH + jj]      = o[r][0];
    ob[(size_t)(i0+r)*DH + jj + 32] = o[r][1];
  }
}

extern "C" void kernel_launch(void* const* d_in, const int* in_sizes, int n_in,
                              void* d_out, int out_size, void* d_ws, size_t ws_size,
                              hipStream_t stream) {
  const float* q = (const float*)d_in[0];
  const float* k = (const float*)d_in[1];
  const float* v = (const float*)d_in[2];
  const float* P = (const float*)d_in[3];
  float* out = (float*)d_out;

  float* wsf   = (float*)d_ws;
  float* qf    = wsf;                    // 2,097,152 floats (q_feat -> q')
  float* kd    = wsf + 2097152;          // 2,097,152 floats (k_dash -> k_feat)
  float* diagk = wsf + 4194304;          // 8192
  float* bmax  = wsf + 4202496;          // 8192
  float* gmaxp = wsf + 4210688;          // 1 (padded to 64)
  float* csum  = wsf + 4210752;          // 16384
  // total ~16.9 MB of workspace

  kq_feat <<<ROWS, 256, 0, stream>>>(q, P, qf);
  kk_dash <<<ROWS, 256, 0, stream>>>(k, P, kd, diagk, bmax);
  kk_gmax <<<1, 256, 0, stream>>>(bmax, gmaxp);
  kk_feat <<<BH*NCHUNK, 256, 0, stream>>>(kd, diagk, gmaxp, csum);
  kq_prime<<<BH*NCHUNK, 256, 0, stream>>>(qf, kd, csum);
  k_attn  <<<dim3(SEQ/RB, BH), 256, 0, stream>>>(qf, kd, v, out);
}

// Round 2
// 293.177 us; speedup vs baseline: 3.1418x; 3.1418x over previous
//
#include <hip/hip_runtime.h>
#include <math.h>

// Problem constants (B=1, H=4, N=2048, D=64, M=256)
#define NH   4
#define SEQ  2048
#define DH   64
#define NF   256
#define ROWS (NH*SEQ)            // 8192
#define DN    0.35355339059327373f   // 64^-0.25
#define DIAGC 0.0625f                // 0.5*DN*DN
#define RATIO 0.0625f                // 1/sqrt(256)
#define EPSF  1e-4f

#define CH     64                // cumsum chunk rows
#define NCH    32                // SEQ/CH

typedef __attribute__((ext_vector_type(8))) short bf8;
typedef __attribute__((ext_vector_type(4))) short bf4;
typedef __attribute__((ext_vector_type(4))) float f4;

static __device__ __forceinline__ unsigned short f2bf(float x) {
  union { float f; unsigned u; } v; v.f = x;
  unsigned r = v.u + 0x7FFF + ((v.u >> 16) & 1);
  return (unsigned short)(r >> 16);
}
static __device__ __forceinline__ float bf2f(unsigned short b) {
  union { unsigned u; float f; } v; v.u = ((unsigned)b) << 16;
  return v.f;
}

// ---------------- q features: dash + rowmax + exp -> bf16 ----------------
__global__ __launch_bounds__(256) void kq_feat(const float* __restrict__ q,
                                               const float* __restrict__ P,
                                               unsigned short* __restrict__ qfb) {
  const int row = blockIdx.x;
  const int m = threadIdx.x;
  __shared__ float sq[DH];
  __shared__ float red[256];
  if (m < DH) sq[m] = q[(size_t)row*DH + m];
  __syncthreads();
  float acc = 0.f, ss = 0.f;
  const float* Pm = P + m*DH;
#pragma unroll
  for (int d = 0; d < DH; ++d) { float x = sq[d]; acc += x*Pm[d]; ss += x*x; }
  float qd = DN * acc;
  red[m] = qd;
  __syncthreads();
  for (int s = 128; s > 0; s >>= 1) {
    if (m < s) red[m] = fmaxf(red[m], red[m+s]);
    __syncthreads();
  }
  qfb[(size_t)row*NF + m] = f2bf(RATIO * (expf(qd - ss*DIAGC - red[0]) + EPSF));
}

// ---------------- k row-max only (k_dash recomputed later) ----------------
__global__ __launch_bounds__(256) void kk_rmax(const float* __restrict__ k,
                                               const float* __restrict__ P,
                                               float* __restrict__ bmax) {
  const int row = blockIdx.x;
  const int m = threadIdx.x;
  __shared__ float sk[DH];
  __shared__ float red[256];
  if (m < DH) sk[m] = k[(size_t)row*DH + m];
  __syncthreads();
  float acc = 0.f;
  const float* Pm = P + m*DH;
#pragma unroll
  for (int d = 0; d < DH; ++d) acc += sk[d]*Pm[d];
  red[m] = DN * acc;
  __syncthreads();
  for (int s = 128; s > 0; s >>= 1) {
    if (m < s) red[m] = fmaxf(red[m], red[m+s]);
    __syncthreads();
  }
  if (m == 0) bmax[row] = red[0];
}

__global__ __launch_bounds__(256) void kk_gmax(const float* __restrict__ bmax,
                                               float* __restrict__ gmaxp) {
  __shared__ float red[256];
  const int t = threadIdx.x;
  float mx = -3.4e38f;
  for (int i = t; i < ROWS; i += 256) mx = fmaxf(mx, bmax[i]);
  red[t] = mx;
  __syncthreads();
  for (int s = 128; s > 0; s >>= 1) {
    if (t < s) red[t] = fmaxf(red[t], red[t+s]);
    __syncthreads();
  }
  if (t == 0) gmaxp[0] = red[0];
}

// ------- k_feat: recompute dash, exp -> bf16, chunk partial sums (fp32) -------
__global__ __launch_bounds__(256) void kk_feat(const float* __restrict__ k,
                                               const float* __restrict__ P,
                                               const float* __restrict__ gmaxp,
                                               unsigned short* __restrict__ kfb,
                                               float* __restrict__ csum) {
  const int bh = blockIdx.x >> 5;
  const int ch = blockIdx.x & 31;
  const int m = threadIdx.x;
  const float g = gmaxp[0];
  const int r0 = bh*SEQ + ch*CH;
  __shared__ float sk[CH][DH];
  for (int i = m; i < CH*DH; i += 256) sk[i>>6][i&63] = k[(size_t)r0*DH + i];
  __syncthreads();
  const float* Pm = P + m*DH;
  float run = 0.f;
  for (int r = 0; r < CH; ++r) {
    float acc = 0.f, ss = 0.f;
#pragma unroll
    for (int d = 0; d < DH; ++d) { float x = sk[r][d]; acc += x*Pm[d]; ss += x*x; }
    unsigned short b = f2bf(RATIO * (expf(DN*acc - ss*DIAGC - g) + EPSF));
    kfb[(size_t)(r0 + r)*NF + m] = b;
    run += bf2f(b);           // accumulate the rounded value (consistent with attn)
  }
  csum[(size_t)(bh*NCH + ch)*NF + m] = run;
}

// -------- q' = q_feat / cumsum(k_feat), in-place bf16 --------
__global__ __launch_bounds__(256) void kq_prime(unsigned short* __restrict__ qfb,
                                                const unsigned short* __restrict__ kfb,
                                                const float* __restrict__ csum) {
  const int bh = blockIdx.x >> 5;
  const int ch = blockIdx.x & 31;
  const int m = threadIdx.x;
  float run = 0.f;
  for (int c = 0; c < ch; ++c) run += csum[(size_t)(bh*NCH + c)*NF + m];
  const int r0 = bh*SEQ + ch*CH;
  for (int r = 0; r < CH; ++r) {
    const size_t idx = (size_t)(r0 + r)*NF + m;
    run += bf2f(kfb[idx]);
    qfb[idx] = f2bf(bf2f(qfb[idx]) / run);
  }
}

// -------- V transpose -> bf16: vtb[h][e][n] --------
__global__ __launch_bounds__(256) void kv_t(const float* __restrict__ v,
                                            unsigned short* __restrict__ vtb) {
  const int h = blockIdx.y, n0 = blockIdx.x*64;
  __shared__ float t[64][65];
  const int tid = threadIdx.x;
  for (int i = tid; i < 4096; i += 256) {
    int n = i >> 6, e = i & 63;
    t[n][e] = v[((size_t)h*SEQ + n0 + n)*DH + e];
  }
  __syncthreads();
  for (int i = tid; i < 4096; i += 256) {
    int e = i >> 6, n = i & 63;
    vtb[((size_t)h*DH + e)*SEQ + n0 + n] = f2bf(t[n][e]);
  }
}

// -------- causal attention, wave-per-(16-row-tile, column-chunk), MFMA --------
// unit = t*4 + c; wave handles col-tiles [c*w, min((c+1)*w, t+1)), w = ceil((t+1)/4)
__global__ __launch_bounds__(256) void k_attn(const unsigned short* __restrict__ qpb,
                                              const unsigned short* __restrict__ kfb,
                                              const unsigned short* __restrict__ vtb,
                                              float* __restrict__ out,
                                              float* __restrict__ part) {
  const int h = blockIdx.y;
  const int wid = threadIdx.x >> 6, lane = threadIdx.x & 63;
  const int unit = blockIdx.x*4 + wid;     // 0..511
  const int t = unit >> 2, c = unit & 3;
  const int nt = t + 1;
  const int w = (nt + 3) >> 2;
  const int j0 = c*w, j1 = (j0 + w < nt) ? (j0 + w) : nt;
  if (j0 >= j1) return;
  const int lr = lane & 15, g = lane >> 4;

  // Q' A-fragments, persistent: row = lane&15, k = kb*32 + g*8 + j
  const unsigned short* qb = qpb + ((size_t)(h*SEQ + t*16 + lr))*NF + g*8;
  bf8 qf[8];
#pragma unroll
  for (int kb = 0; kb < 8; ++kb) qf[kb] = *(const bf8*)(qb + kb*32);

  f4 o0 = {0,0,0,0}, o1 = {0,0,0,0}, o2 = {0,0,0,0}, o3 = {0,0,0,0};

  const unsigned short* vbase = vtb + (size_t)h*DH*SEQ + (size_t)lr*SEQ;

  for (int j = j0; j < j1; ++j) {
    // S^T = Kf * Q'^T : D[kcol][qrow]; C-layout: qrow=lane&15, kcol=4g+r
    const unsigned short* kb_ = kfb + ((size_t)(h*SEQ + j*16 + lr))*NF + g*8;
    f4 st = {0,0,0,0};
#pragma unroll
    for (int kb = 0; kb < 8; ++kb) {
      bf8 kfr = *(const bf8*)(kb_ + kb*32);
      st = __builtin_amdgcn_mfma_f32_16x16x32_bf16(kfr, qf[kb], st, 0, 0, 0);
    }
    if (j == t) {   // causal mask on the diagonal tile
#pragma unroll
      for (int r = 0; r < 4; ++r) if (g*4 + r > lr) st[r] = 0.f;
    }
    // S^T C-frag == A-frag of S for PV (qrow=lane&15, kcol slots 4g+r); zero-pad to K=32
    bf8 sb = { (short)f2bf(st[0]), (short)f2bf(st[1]), (short)f2bf(st[2]), (short)f2bf(st[3]),
               (short)0, (short)0, (short)0, (short)0 };
    const unsigned short* vb = vbase + j*16 + g*4;
#pragma unroll
    for (int eb = 0; eb < 4; ++eb) {
      bf4 v4 = *(const bf4*)(vb + (size_t)eb*16*SEQ);
      bf8 vf = { v4[0], v4[1], v4[2], v4[3], (short)0, (short)0, (short)0, (short)0 };
      f4 acc = (eb == 0) ? o0 : (eb == 1) ? o1 : (eb == 2) ? o2 : o3;
      acc = __builtin_amdgcn_mfma_f32_16x16x32_bf16(sb, vf, acc, 0, 0, 0);
      if (eb == 0) o0 = acc; else if (eb == 1) o1 = acc; else if (eb == 2) o2 = acc; else o3 = acc;
    }
  }

  // O C-layout: e-col = eb*16 + (lane&15), qrow = 4g + r
  if (c == 0) {
    float* ob = out + ((size_t)(h*SEQ + t*16))*DH;
#pragma unroll
    for (int r = 0; r < 4; ++r) {
      ob[(size_t)(4*g + r)*DH +  0 + lr] = o0[r];
      ob[(size_t)(4*g + r)*DH + 16 + lr] = o1[r];
      ob[(size_t)(4*g + r)*DH + 32 + lr] = o2[r];
      ob[(size_t)(4*g + r)*DH + 48 + lr] = o3[r];
    }
  } else {
    float* pb = part + ((size_t)((h*128 + t)*3 + (c - 1)))*1024;
#pragma unroll
    for (int r = 0; r < 4; ++r) {
      pb[(size_t)(4*g + r)*DH +  0 + lr] = o0[r];
      pb[(size_t)(4*g + r)*DH + 16 + lr] = o1[r];
      pb[(size_t)(4*g + r)*DH + 32 + lr] = o2[r];
      pb[(size_t)(4*g + r)*DH + 48 + lr] = o3[r];
    }
  }
}

// -------- add partials (chunks 1..3) into out --------
__global__ __launch_bounds__(256) void k_red(float* __restrict__ out,
                                             const float* __restrict__ part) {
  const int idx = blockIdx.x*256 + threadIdx.x;   // 524288 total
  const int row = idx >> 6, e = idx & 63;
  const int h = row >> 11, n = row & 2047;
  const int t = n >> 4, lr = n & 15;
  const int nt = t + 1, w = (nt + 3) >> 2;
  float s = out[idx];
  for (int c = 1; c < 4; ++c) {
    if (c*w < nt)
      s += part[((size_t)((h*128 + t)*3 + (c - 1)))*1024 + (size_t)lr*64 + e];
  }
  out[idx] = s;
}

extern "C" void kernel_launch(void* const* d_in, const int* in_sizes, int n_in,
                              void* d_out, int out_size, void* d_ws, size_t ws_size,
                              hipStream_t stream) {
  const float* q = (const float*)d_in[0];
  const float* k = (const float*)d_in[1];
  const float* v = (const float*)d_in[2];
  const float* P = (const float*)d_in[3];
  float* out = (float*)d_out;

  char* ws = (char*)d_ws;
  unsigned short* qfb = (unsigned short*)(ws + 0);          // 4 MB  (q_feat -> q')
  unsigned short* kfb = (unsigned short*)(ws + 4194304);    // 4 MB  (k_feat bf16)
  unsigned short* vtb = (unsigned short*)(ws + 8388608);    // 1 MB  (V^T bf16)
  float* part = (float*)(ws + 9437184);                     // 6 MB  (partials)
  float* bmax = (float*)(ws + 15728640);                    // 32 KB
  float* gmaxp = (float*)(ws + 15761408);                   // 256 B
  float* csum = (float*)(ws + 15761664);                    // 128 KB
  // total ~15.2 MB

  kq_feat <<<ROWS, 256, 0, stream>>>(q, P, qfb);
  kk_rmax <<<ROWS, 256, 0, stream>>>(k, P, bmax);
  kk_gmax <<<1, 256, 0, stream>>>(bmax, gmaxp);
  kk_feat <<<NH*NCH, 256, 0, stream>>>(k, P, gmaxp, kfb, csum);
  kq_prime<<<NH*NCH, 256, 0, stream>>>(qfb, kfb, csum);
  kv_t    <<<dim3(SEQ/64, NH), 256, 0, stream>>>(v, vtb);
  k_attn  <<<dim3(128, NH), 256, 0, stream>>>(qfb, kfb, vtb, out, part);
  k_red   <<<2048, 256, 0, stream>>>(out, part);
}

// Round 3
// 161.056 us; speedup vs baseline: 5.7192x; 1.8203x over previous
//
#include <hip/hip_runtime.h>
#include <math.h>

// Problem constants (B=1, H=4, N=2048, D=64, M=256)
#define NH   4
#define SEQ  2048
#define DH   64
#define NF   256
#define ROWS (NH*SEQ)                // 8192
#define DN    0.35355339059327373f   // 64^-0.25
#define DIAGC 0.0625f                // 0.5*DN*DN
#define RATIO 0.0625f                // 1/sqrt(256)
#define EPSF  1e-4f

typedef __attribute__((ext_vector_type(8))) short bf8;
typedef __attribute__((ext_vector_type(4))) short bf4;
typedef __attribute__((ext_vector_type(4))) float f4;

static __device__ __forceinline__ unsigned short f2bf(float x) {
  union { float f; unsigned u; } v; v.f = x;
  unsigned r = v.u + 0x7FFF + ((v.u >> 16) & 1);
  return (unsigned short)(r >> 16);
}
static __device__ __forceinline__ float bf2f(unsigned short b) {
  union { unsigned u; float f; } v; v.u = ((unsigned)b) << 16;
  return v.f;
}

// ---------------- P -> bf16 hi/lo split ----------------
__global__ __launch_bounds__(256) void fp_prep(const float* __restrict__ P,
                                               unsigned short* __restrict__ phi,
                                               unsigned short* __restrict__ plo) {
  int i = blockIdx.x*256 + threadIdx.x;   // < 16384
  float p = P[i];
  unsigned short h = f2bf(p);
  phi[i] = h;
  plo[i] = f2bf(p - bf2f(h));
}

// ---- shared projection core: one wave computes dash for a 16-row tile ----
// dsh[ct][r] = dash[row=4g+r][feat=ct*16+lr]; ssf = sum(x^2) for row lr.
static __device__ __forceinline__ void proj_tile(const float* __restrict__ x,
    const unsigned short* __restrict__ phi, const unsigned short* __restrict__ plo,
    int lr, int g, f4 dsh[16], float& ssf) {
  f4 a = *(const f4*)(x + lr*DH + g*8);
  f4 b = *(const f4*)(x + lr*DH + g*8 + 4);
  f4 c = *(const f4*)(x + lr*DH + 32 + g*8);
  f4 d = *(const f4*)(x + lr*DH + 32 + g*8 + 4);
  float ss = 0.f;
#pragma unroll
  for (int i = 0; i < 4; ++i) ss += a[i]*a[i] + b[i]*b[i] + c[i]*c[i] + d[i]*d[i];
  ss += __shfl_xor(ss, 16);
  ss += __shfl_xor(ss, 32);
  ssf = ss;   // full sum(x^2) of row lr, at every lane
  bf8 xh0, xh1, xl0, xl1;
#pragma unroll
  for (int i = 0; i < 4; ++i) {
    float v0 = DN*a[i], v1 = DN*b[i], v2 = DN*c[i], v3 = DN*d[i];
    unsigned short h0 = f2bf(v0), h1 = f2bf(v1), h2 = f2bf(v2), h3 = f2bf(v3);
    xh0[i] = (short)h0; xh0[i+4] = (short)h1;
    xh1[i] = (short)h2; xh1[i+4] = (short)h3;
    xl0[i]   = (short)f2bf(v0 - bf2f(h0)); xl0[i+4] = (short)f2bf(v1 - bf2f(h1));
    xl1[i]   = (short)f2bf(v2 - bf2f(h2)); xl1[i+4] = (short)f2bf(v3 - bf2f(h3));
  }
#pragma unroll
  for (int ct = 0; ct < 16; ++ct) {
    const unsigned short* pr = phi + (ct*16 + lr)*DH + g*8;
    const unsigned short* pl = plo + (ct*16 + lr)*DH + g*8;
    bf8 bh0 = *(const bf8*)(pr);
    bf8 bh1 = *(const bf8*)(pr + 32);
    bf8 bl0 = *(const bf8*)(pl);
    bf8 bl1 = *(const bf8*)(pl + 32);
    f4 acc = {0.f, 0.f, 0.f, 0.f};
    acc = __builtin_amdgcn_mfma_f32_16x16x32_bf16(xh0, bh0, acc, 0, 0, 0);
    acc = __builtin_amdgcn_mfma_f32_16x16x32_bf16(xh1, bh1, acc, 0, 0, 0);
    acc = __builtin_amdgcn_mfma_f32_16x16x32_bf16(xh0, bl0, acc, 0, 0, 0);
    acc = __builtin_amdgcn_mfma_f32_16x16x32_bf16(xh1, bl1, acc, 0, 0, 0);
    acc = __builtin_amdgcn_mfma_f32_16x16x32_bf16(xl0, bh0, acc, 0, 0, 0);
    acc = __builtin_amdgcn_mfma_f32_16x16x32_bf16(xl1, bh1, acc, 0, 0, 0);
    dsh[ct] = acc;
  }
}

// ---- q features (full) + k row-maxes, fused: units 0..511 q, 512..1023 k ----
__global__ __launch_bounds__(256) void k_projQK(const float* __restrict__ q,
    const float* __restrict__ k, const unsigned short* __restrict__ phi,
    const unsigned short* __restrict__ plo, unsigned short* __restrict__ qfb,
    float* __restrict__ bmax) {
  const int wid = threadIdx.x >> 6, lane = threadIdx.x & 63;
  const int unit = blockIdx.x*4 + wid;       // 0..1023
  const int lr = lane & 15, g = lane >> 4;
  const bool isq = unit < 512;
  const int tile = isq ? unit : unit - 512;  // h*128 + t
  const float* x = (isq ? q : k) + (size_t)tile*16*DH;
  f4 dsh[16]; float ssf;
  proj_tile(x, phi, plo, lr, g, dsh, ssf);
  float m0 = -3.4e38f, m1 = -3.4e38f, m2 = -3.4e38f, m3 = -3.4e38f;
#pragma unroll
  for (int ct = 0; ct < 16; ++ct) {
    m0 = fmaxf(m0, dsh[ct][0]); m1 = fmaxf(m1, dsh[ct][1]);
    m2 = fmaxf(m2, dsh[ct][2]); m3 = fmaxf(m3, dsh[ct][3]);
  }
#pragma unroll
  for (int mk = 1; mk <= 8; mk <<= 1) {
    m0 = fmaxf(m0, __shfl_xor(m0, mk)); m1 = fmaxf(m1, __shfl_xor(m1, mk));
    m2 = fmaxf(m2, __shfl_xor(m2, mk)); m3 = fmaxf(m3, __shfl_xor(m3, mk));
  }
  if (isq) {
    float d0 = __shfl(ssf, 4*g + 0)*DIAGC + m0;
    float d1 = __shfl(ssf, 4*g + 1)*DIAGC + m1;
    float d2 = __shfl(ssf, 4*g + 2)*DIAGC + m2;
    float d3 = __shfl(ssf, 4*g + 3)*DIAGC + m3;
    unsigned short* ob = qfb + (size_t)(tile*16)*NF;
#pragma unroll
    for (int ct = 0; ct < 16; ++ct) {
      ob[(4*g + 0)*NF + ct*16 + lr] = f2bf(RATIO*(expf(dsh[ct][0] - d0) + EPSF));
      ob[(4*g + 1)*NF + ct*16 + lr] = f2bf(RATIO*(expf(dsh[ct][1] - d1) + EPSF));
      ob[(4*g + 2)*NF + ct*16 + lr] = f2bf(RATIO*(expf(dsh[ct][2] - d2) + EPSF));
      ob[(4*g + 3)*NF + ct*16 + lr] = f2bf(RATIO*(expf(dsh[ct][3] - d3) + EPSF));
    }
  } else {
    if (lr == 0) {
      bmax[tile*16 + 4*g + 0] = m0;
      bmax[tile*16 + 4*g + 1] = m1;
      bmax[tile*16 + 4*g + 2] = m2;
      bmax[tile*16 + 4*g + 3] = m3;
    }
  }
}

__global__ __launch_bounds__(256) void kk_gmax(const float* __restrict__ bmax,
                                               float* __restrict__ gmaxp) {
  __shared__ float red[256];
  const int t = threadIdx.x;
  float mx = -3.4e38f;
  for (int i = t; i < ROWS; i += 256) mx = fmaxf(mx, bmax[i]);
  red[t] = mx;
  __syncthreads();
  for (int s = 128; s > 0; s >>= 1) {
    if (t < s) red[t] = fmaxf(red[t], red[t+s]);
    __syncthreads();
  }
  if (t == 0) gmaxp[0] = red[0];
}

// ---- k features (global stab) -> kfb bf16 + per-16-row-tile feature sums ----
__global__ __launch_bounds__(256) void k_projKF(const float* __restrict__ k,
    const unsigned short* __restrict__ phi, const unsigned short* __restrict__ plo,
    const float* __restrict__ gmaxp, unsigned short* __restrict__ kfb,
    float* __restrict__ csum) {
  const int wid = threadIdx.x >> 6, lane = threadIdx.x & 63;
  const int unit = blockIdx.x*4 + wid;   // 0..511 = h*128 + t
  const int lr = lane & 15, g = lane >> 4;
  const float* x = k + (size_t)unit*16*DH;
  f4 dsh[16]; float ssf;
  proj_tile(x, phi, plo, lr, g, dsh, ssf);
  const float gst = gmaxp[0];
  float d0 = __shfl(ssf, 4*g + 0)*DIAGC + gst;
  float d1 = __shfl(ssf, 4*g + 1)*DIAGC + gst;
  float d2 = __shfl(ssf, 4*g + 2)*DIAGC + gst;
  float d3 = __shfl(ssf, 4*g + 3)*DIAGC + gst;
  unsigned short* ob = kfb + (size_t)(unit*16)*NF;
#pragma unroll
  for (int ct = 0; ct < 16; ++ct) {
    unsigned short u0 = f2bf(RATIO*(expf(dsh[ct][0] - d0) + EPSF));
    unsigned short u1 = f2bf(RATIO*(expf(dsh[ct][1] - d1) + EPSF));
    unsigned short u2 = f2bf(RATIO*(expf(dsh[ct][2] - d2) + EPSF));
    unsigned short u3 = f2bf(RATIO*(expf(dsh[ct][3] - d3) + EPSF));
    ob[(4*g + 0)*NF + ct*16 + lr] = u0;
    ob[(4*g + 1)*NF + ct*16 + lr] = u1;
    ob[(4*g + 2)*NF + ct*16 + lr] = u2;
    ob[(4*g + 3)*NF + ct*16 + lr] = u3;
    float cs = bf2f(u0) + bf2f(u1) + bf2f(u2) + bf2f(u3);
    cs += __shfl_xor(cs, 16);
    cs += __shfl_xor(cs, 32);
    if (g == 0) csum[(size_t)unit*NF + ct*16 + lr] = cs;
  }
}

// ---- exclusive scan of per-tile sums over the 128 tiles of each head ----
__global__ __launch_bounds__(256) void k_scan(float* __restrict__ csum) {
  const int h = blockIdx.x, m = threadIdx.x;
  float run = 0.f;
#pragma unroll 8
  for (int c = 0; c < 128; ++c) {
    size_t idx = (size_t)(h*128 + c)*NF + m;
    float x = csum[idx];
    csum[idx] = run;
    run += x;
  }
}

// ---- q' = q_feat / cumsum(k_feat), in place over qfb ----
__global__ __launch_bounds__(256) void k_prime(unsigned short* __restrict__ qfb,
    const unsigned short* __restrict__ kfb, const float* __restrict__ csum) {
  const int u = blockIdx.x;        // 0..511 = h*128 + t
  const int m = threadIdx.x;
  float run = csum[(size_t)u*NF + m];
#pragma unroll
  for (int r = 0; r < 16; ++r) {
    size_t idx = (size_t)(u*16 + r)*NF + m;
    run += bf2f(kfb[idx]);
    qfb[idx] = f2bf(bf2f(qfb[idx]) / run);
  }
}

// ---- V transpose -> bf16: vtb[h][e][n] ----
__global__ __launch_bounds__(256) void kv_t(const float* __restrict__ v,
                                            unsigned short* __restrict__ vtb) {
  const int h = blockIdx.y, n0 = blockIdx.x*64;
  __shared__ float t[64][65];
  const int tid = threadIdx.x;
  for (int i = tid; i < 4096; i += 256) {
    int n = i >> 6, e = i & 63;
    t[n][e] = v[((size_t)h*SEQ + n0 + n)*DH + e];
  }
  __syncthreads();
  for (int i = tid; i < 4096; i += 256) {
    int e = i >> 6, n = i & 63;
    vtb[((size_t)h*DH + e)*SEQ + n0 + n] = f2bf(t[n][e]);
  }
}

// ---- causal attention: wave per (16-row tile, 16-j-tile chunk), prefetched ----
__global__ __launch_bounds__(256) void k_attn(const unsigned short* __restrict__ qpb,
                                              const unsigned short* __restrict__ kfb,
                                              const unsigned short* __restrict__ vtb,
                                              float* __restrict__ out,
                                              float* __restrict__ part) {
  const int h = blockIdx.y;
  const int wid = threadIdx.x >> 6, lane = threadIdx.x & 63;
  const int u = blockIdx.x*4 + wid;        // 0..1023
  const int t = u >> 3, c = u & 7;
  const int cmax = (t + 16) >> 4;          // ceil((t+1)/16)
  if (c >= cmax) return;
  const int j0 = c*16;
  const int j1 = (j0 + 16 < t + 1) ? j0 + 16 : t + 1;
  const int lr = lane & 15, g = lane >> 4;

  const unsigned short* qb = qpb + ((size_t)(h*SEQ + t*16 + lr))*NF + g*8;
  bf8 qf[8];
#pragma unroll
  for (int kb = 0; kb < 8; ++kb) qf[kb] = *(const bf8*)(qb + kb*32);

  const unsigned short* kbase = kfb + ((size_t)h*SEQ + lr)*NF + g*8;
  const unsigned short* vbase = vtb + ((size_t)h*DH + lr)*SEQ + g*4;

  f4 o0 = {0,0,0,0}, o1 = {0,0,0,0}, o2 = {0,0,0,0}, o3 = {0,0,0,0};

  bf8 kc[8]; bf4 vc[4];
  {
    const unsigned short* kp = kbase + (size_t)j0*16*NF;
#pragma unroll
    for (int kb = 0; kb < 8; ++kb) kc[kb] = *(const bf8*)(kp + kb*32);
    const unsigned short* vp = vbase + j0*16;
#pragma unroll
    for (int eb = 0; eb < 4; ++eb) vc[eb] = *(const bf4*)(vp + (size_t)eb*16*SEQ);
  }

  for (int j = j0; j < j1; ++j) {
    const int jn = (j + 1 < j1) ? j + 1 : j;
    bf8 kn[8]; bf4 vn[4];
    const unsigned short* kp = kbase + (size_t)jn*16*NF;
#pragma unroll
    for (int kb = 0; kb < 8; ++kb) kn[kb] = *(const bf8*)(kp + kb*32);
    const unsigned short* vp = vbase + jn*16;
#pragma unroll
    for (int eb = 0; eb < 4; ++eb) vn[eb] = *(const bf4*)(vp + (size_t)eb*16*SEQ);

    f4 st = {0,0,0,0};
#pragma unroll
    for (int kb = 0; kb < 8; ++kb)
      st = __builtin_amdgcn_mfma_f32_16x16x32_bf16(kc[kb], qf[kb], st, 0, 0, 0);
    if (j == t) {
#pragma unroll
      for (int r = 0; r < 4; ++r) if (g*4 + r > lr) st[r] = 0.f;
    }
    bf8 sb = { (short)f2bf(st[0]), (short)f2bf(st[1]), (short)f2bf(st[2]), (short)f2bf(st[3]),
               (short)0, (short)0, (short)0, (short)0 };
    bf8 vf0 = { vc[0][0], vc[0][1], vc[0][2], vc[0][3], (short)0, (short)0, (short)0, (short)0 };
    bf8 vf1 = { vc[1][0], vc[1][1], vc[1][2], vc[1][3], (short)0, (short)0, (short)0, (short)0 };
    bf8 vf2 = { vc[2][0], vc[2][1], vc[2][2], vc[2][3], (short)0, (short)0, (short)0, (short)0 };
    bf8 vf3 = { vc[3][0], vc[3][1], vc[3][2], vc[3][3], (short)0, (short)0, (short)0, (short)0 };
    o0 = __builtin_amdgcn_mfma_f32_16x16x32_bf16(sb, vf0, o0, 0, 0, 0);
    o1 = __builtin_amdgcn_mfma_f32_16x16x32_bf16(sb, vf1, o1, 0, 0, 0);
    o2 = __builtin_amdgcn_mfma_f32_16x16x32_bf16(sb, vf2, o2, 0, 0, 0);
    o3 = __builtin_amdgcn_mfma_f32_16x16x32_bf16(sb, vf3, o3, 0, 0, 0);
#pragma unroll
    for (int kb = 0; kb < 8; ++kb) kc[kb] = kn[kb];
#pragma unroll
    for (int eb = 0; eb < 4; ++eb) vc[eb] = vn[eb];
  }

  float* ob;
  if (c == 0) {
    ob = out + ((size_t)(h*SEQ + t*16))*DH;
  } else {
    const int qt = t >> 4, rt = t & 15;
    const int Pt = 8*qt*(qt+1) + rt*(qt+1) - t;   // compact partial index
    ob = part + ((size_t)(h*448 + Pt + (c-1)))*1024;
  }
#pragma unroll
  for (int r = 0; r < 4; ++r) {
    ob[(size_t)(4*g + r)*DH +  0 + lr] = o0[r];
    ob[(size_t)(4*g + r)*DH + 16 + lr] = o1[r];
    ob[(size_t)(4*g + r)*DH + 32 + lr] = o2[r];
    ob[(size_t)(4*g + r)*DH + 48 + lr] = o3[r];
  }
}

// ---- add partial chunks into out ----
__global__ __launch_bounds__(256) void k_red(float* __restrict__ out,
                                             const float* __restrict__ part) {
  const int idx = blockIdx.x*256 + threadIdx.x;   // 524288
  const int e = idx & 63, row = idx >> 6;
  const int h = row >> 11, n = row & 2047;
  const int t = n >> 4, lr = n & 15;
  const int cmax = (t + 16) >> 4;
  if (cmax <= 1) return;
  const int qt = t >> 4, rt = t & 15;
  const int Pt = 8*qt*(qt+1) + rt*(qt+1) - t;
  float s = out[idx];
#pragma unroll
  for (int c = 1; c < 8; ++c)
    if (c < cmax)
      s += part[((size_t)(h*448 + Pt + (c-1)))*1024 + (size_t)lr*64 + e];
  out[idx] = s;
}

extern "C" void kernel_launch(void* const* d_in, const int* in_sizes, int n_in,
                              void* d_out, int out_size, void* d_ws, size_t ws_size,
                              hipStream_t stream) {
  const float* q = (const float*)d_in[0];
  const float* k = (const float*)d_in[1];
  const float* v = (const float*)d_in[2];
  const float* P = (const float*)d_in[3];
  float* out = (float*)d_out;

  char* ws = (char*)d_ws;
  unsigned short* qfb = (unsigned short*)(ws);              // 4 MB
  unsigned short* kfb = (unsigned short*)(ws + 4194304);    // 4 MB
  unsigned short* vtb = (unsigned short*)(ws + 8388608);    // 1 MB
  // attn-phase region [9437184, 16777216): partials (7.34 MB).
  // Overlapped (feature-phase only, dead before k_attn): bmax/gmax/csum/phi/plo.
  float* part  = (float*)(ws + 9437184);
  float* bmax  = (float*)(ws + 9437184);                    // 32 KB
  float* gmaxp = (float*)(ws + 9469952);                    // 256 B
  float* csum  = (float*)(ws + 9470208);                    // 512 KB
  unsigned short* phi = (unsigned short*)(ws + 9994496);    // 32 KB
  unsigned short* plo = (unsigned short*)(ws + 10027264);   // 32 KB
  // peak usage: 16 MB

  fp_prep <<<64, 256, 0, stream>>>(P, phi, plo);
  k_projQK<<<256, 256, 0, stream>>>(q, k, phi, plo, qfb, bmax);
  kk_gmax <<<1, 256, 0, stream>>>(bmax, gmaxp);
  k_projKF<<<128, 256, 0, stream>>>(k, phi, plo, gmaxp, kfb, csum);
  k_scan  <<<4, 256, 0, stream>>>(csum);
  k_prime <<<512, 256, 0, stream>>>(qfb, kfb, csum);
  kv_t    <<<dim3(SEQ/64, NH), 256, 0, stream>>>(v, vtb);
  k_attn  <<<dim3(256, NH), 256, 0, stream>>>(qfb, kfb, vtb, out, part);
  k_red   <<<2048, 256, 0, stream>>>(out, part);
}

// Round 4
// 86.512 us; speedup vs baseline: 10.6472x; 1.8617x over previous
//
#include <hip/hip_runtime.h>
#include <math.h>

// Problem constants (B=1, H=4, N=2048, D=64, M=256)
#define NH   4
#define SEQ  2048
#define DH   64
#define NF   256
#define ROWS (NH*SEQ)                // 8192
#define DN    0.35355339059327373f   // 64^-0.25
#define DIAGC 0.0625f                // 0.5*DN*DN
#define RATIO 0.0625f                // 1/sqrt(256)
#define EPSF  1e-4f

typedef __attribute__((ext_vector_type(8))) short bf8;
typedef __attribute__((ext_vector_type(4))) short bf4;
typedef __attribute__((ext_vector_type(4))) float f4;
typedef __attribute__((ext_vector_type(2))) unsigned int u32x2;

static __device__ __forceinline__ unsigned short f2bf(float x) {
  union { float f; unsigned u; } v; v.f = x;
  unsigned r = v.u + 0x7FFF + ((v.u >> 16) & 1);
  return (unsigned short)(r >> 16);
}
static __device__ __forceinline__ float bf2f(unsigned short b) {
  union { unsigned u; float f; } v; v.u = ((unsigned)b) << 16;
  return v.f;
}

// ---------------- P -> bf16 hi/lo split ----------------
__global__ __launch_bounds__(256) void fp_prep(const float* __restrict__ P,
                                               unsigned short* __restrict__ phi,
                                               unsigned short* __restrict__ plo) {
  int i = blockIdx.x*256 + threadIdx.x;   // < 16384
  float p = P[i];
  unsigned short h = f2bf(p);
  phi[i] = h;
  plo[i] = f2bf(p - bf2f(h));
}

// ---- shared projection core: one wave computes dash for a 16-row tile ----
static __device__ __forceinline__ void proj_tile(const float* __restrict__ x,
    const unsigned short* __restrict__ phi, const unsigned short* __restrict__ plo,
    int lr, int g, f4 dsh[16], float& ssf) {
  f4 a = *(const f4*)(x + lr*DH + g*8);
  f4 b = *(const f4*)(x + lr*DH + g*8 + 4);
  f4 c = *(const f4*)(x + lr*DH + 32 + g*8);
  f4 d = *(const f4*)(x + lr*DH + 32 + g*8 + 4);
  float ss = 0.f;
#pragma unroll
  for (int i = 0; i < 4; ++i) ss += a[i]*a[i] + b[i]*b[i] + c[i]*c[i] + d[i]*d[i];
  ss += __shfl_xor(ss, 16);
  ss += __shfl_xor(ss, 32);
  ssf = ss;
  bf8 xh0, xh1, xl0, xl1;
#pragma unroll
  for (int i = 0; i < 4; ++i) {
    float v0 = DN*a[i], v1 = DN*b[i], v2 = DN*c[i], v3 = DN*d[i];
    unsigned short h0 = f2bf(v0), h1 = f2bf(v1), h2 = f2bf(v2), h3 = f2bf(v3);
    xh0[i] = (short)h0; xh0[i+4] = (short)h1;
    xh1[i] = (short)h2; xh1[i+4] = (short)h3;
    xl0[i]   = (short)f2bf(v0 - bf2f(h0)); xl0[i+4] = (short)f2bf(v1 - bf2f(h1));
    xl1[i]   = (short)f2bf(v2 - bf2f(h2)); xl1[i+4] = (short)f2bf(v3 - bf2f(h3));
  }
#pragma unroll
  for (int ct = 0; ct < 16; ++ct) {
    const unsigned short* pr = phi + (ct*16 + lr)*DH + g*8;
    const unsigned short* pl = plo + (ct*16 + lr)*DH + g*8;
    bf8 bh0 = *(const bf8*)(pr);
    bf8 bh1 = *(const bf8*)(pr + 32);
    bf8 bl0 = *(const bf8*)(pl);
    bf8 bl1 = *(const bf8*)(pl + 32);
    f4 acc = {0.f, 0.f, 0.f, 0.f};
    acc = __builtin_amdgcn_mfma_f32_16x16x32_bf16(xh0, bh0, acc, 0, 0, 0);
    acc = __builtin_amdgcn_mfma_f32_16x16x32_bf16(xh1, bh1, acc, 0, 0, 0);
    acc = __builtin_amdgcn_mfma_f32_16x16x32_bf16(xh0, bl0, acc, 0, 0, 0);
    acc = __builtin_amdgcn_mfma_f32_16x16x32_bf16(xh1, bl1, acc, 0, 0, 0);
    acc = __builtin_amdgcn_mfma_f32_16x16x32_bf16(xl0, bh0, acc, 0, 0, 0);
    acc = __builtin_amdgcn_mfma_f32_16x16x32_bf16(xl1, bh1, acc, 0, 0, 0);
    dsh[ct] = acc;
  }
}

// ---- q features (full) + k row-maxes, fused ----
__global__ __launch_bounds__(256) void k_projQK(const float* __restrict__ q,
    const float* __restrict__ k, const unsigned short* __restrict__ phi,
    const unsigned short* __restrict__ plo, unsigned short* __restrict__ qfb,
    float* __restrict__ bmax) {
  const int wid = threadIdx.x >> 6, lane = threadIdx.x & 63;
  const int unit = blockIdx.x*4 + wid;       // 0..1023
  const int lr = lane & 15, g = lane >> 4;
  const bool isq = unit < 512;
  const int tile = isq ? unit : unit - 512;
  const float* x = (isq ? q : k) + (size_t)tile*16*DH;
  f4 dsh[16]; float ssf;
  proj_tile(x, phi, plo, lr, g, dsh, ssf);
  float m0 = -3.4e38f, m1 = -3.4e38f, m2 = -3.4e38f, m3 = -3.4e38f;
#pragma unroll
  for (int ct = 0; ct < 16; ++ct) {
    m0 = fmaxf(m0, dsh[ct][0]); m1 = fmaxf(m1, dsh[ct][1]);
    m2 = fmaxf(m2, dsh[ct][2]); m3 = fmaxf(m3, dsh[ct][3]);
  }
#pragma unroll
  for (int mk = 1; mk <= 8; mk <<= 1) {
    m0 = fmaxf(m0, __shfl_xor(m0, mk)); m1 = fmaxf(m1, __shfl_xor(m1, mk));
    m2 = fmaxf(m2, __shfl_xor(m2, mk)); m3 = fmaxf(m3, __shfl_xor(m3, mk));
  }
  if (isq) {
    float d0 = __shfl(ssf, 4*g + 0)*DIAGC + m0;
    float d1 = __shfl(ssf, 4*g + 1)*DIAGC + m1;
    float d2 = __shfl(ssf, 4*g + 2)*DIAGC + m2;
    float d3 = __shfl(ssf, 4*g + 3)*DIAGC + m3;
    unsigned short* ob = qfb + (size_t)(tile*16)*NF;
#pragma unroll
    for (int ct = 0; ct < 16; ++ct) {
      ob[(4*g + 0)*NF + ct*16 + lr] = f2bf(RATIO*(expf(dsh[ct][0] - d0) + EPSF));
      ob[(4*g + 1)*NF + ct*16 + lr] = f2bf(RATIO*(expf(dsh[ct][1] - d1) + EPSF));
      ob[(4*g + 2)*NF + ct*16 + lr] = f2bf(RATIO*(expf(dsh[ct][2] - d2) + EPSF));
      ob[(4*g + 3)*NF + ct*16 + lr] = f2bf(RATIO*(expf(dsh[ct][3] - d3) + EPSF));
    }
  } else {
    if (lr == 0) {
      bmax[tile*16 + 4*g + 0] = m0;
      bmax[tile*16 + 4*g + 1] = m1;
      bmax[tile*16 + 4*g + 2] = m2;
      bmax[tile*16 + 4*g + 3] = m3;
    }
  }
}

__global__ __launch_bounds__(256) void kk_gmax(const float* __restrict__ bmax,
                                               float* __restrict__ gmaxp) {
  __shared__ float red[256];
  const int t = threadIdx.x;
  float mx = -3.4e38f;
  for (int i = t; i < ROWS; i += 256) mx = fmaxf(mx, bmax[i]);
  red[t] = mx;
  __syncthreads();
  for (int s = 128; s > 0; s >>= 1) {
    if (t < s) red[t] = fmaxf(red[t], red[t+s]);
    __syncthreads();
  }
  if (t == 0) gmaxp[0] = red[0];
}

// ---- k features (global stab) -> kfb bf16 + per-16-row-tile feature sums ----
__global__ __launch_bounds__(256) void k_projKF(const float* __restrict__ k,
    const unsigned short* __restrict__ phi, const unsigned short* __restrict__ plo,
    const float* __restrict__ gmaxp, unsigned short* __restrict__ kfb,
    float* __restrict__ csum) {
  const int wid = threadIdx.x >> 6, lane = threadIdx.x & 63;
  const int unit = blockIdx.x*4 + wid;   // 0..511 = h*128 + t
  const int lr = lane & 15, g = lane >> 4;
  const float* x = k + (size_t)unit*16*DH;
  f4 dsh[16]; float ssf;
  proj_tile(x, phi, plo, lr, g, dsh, ssf);
  const float gst = gmaxp[0];
  float d0 = __shfl(ssf, 4*g + 0)*DIAGC + gst;
  float d1 = __shfl(ssf, 4*g + 1)*DIAGC + gst;
  float d2 = __shfl(ssf, 4*g + 2)*DIAGC + gst;
  float d3 = __shfl(ssf, 4*g + 3)*DIAGC + gst;
  unsigned short* ob = kfb + (size_t)(unit*16)*NF;
#pragma unroll
  for (int ct = 0; ct < 16; ++ct) {
    unsigned short u0 = f2bf(RATIO*(expf(dsh[ct][0] - d0) + EPSF));
    unsigned short u1 = f2bf(RATIO*(expf(dsh[ct][1] - d1) + EPSF));
    unsigned short u2 = f2bf(RATIO*(expf(dsh[ct][2] - d2) + EPSF));
    unsigned short u3 = f2bf(RATIO*(expf(dsh[ct][3] - d3) + EPSF));
    ob[(4*g + 0)*NF + ct*16 + lr] = u0;
    ob[(4*g + 1)*NF + ct*16 + lr] = u1;
    ob[(4*g + 2)*NF + ct*16 + lr] = u2;
    ob[(4*g + 3)*NF + ct*16 + lr] = u3;
    float cs = bf2f(u0) + bf2f(u1) + bf2f(u2) + bf2f(u3);
    cs += __shfl_xor(cs, 16);
    cs += __shfl_xor(cs, 32);
    if (g == 0) csum[(size_t)unit*NF + ct*16 + lr] = cs;
  }
}

// ---- exclusive scan of per-tile sums over the 128 tiles of each head ----
__global__ __launch_bounds__(256) void k_scan(float* __restrict__ csum) {
  const int h = blockIdx.x, m = threadIdx.x;
  float run = 0.f;
#pragma unroll 8
  for (int c = 0; c < 128; ++c) {
    size_t idx = (size_t)(h*128 + c)*NF + m;
    float x = csum[idx];
    csum[idx] = run;
    run += x;
  }
}

// ---- q' = q_feat / cumsum(k_feat), in place over qfb ----
__global__ __launch_bounds__(256) void k_prime(unsigned short* __restrict__ qfb,
    const unsigned short* __restrict__ kfb, const float* __restrict__ csum) {
  const int u = blockIdx.x;        // 0..511 = h*128 + t
  const int m = threadIdx.x;
  float run = csum[(size_t)u*NF + m];
#pragma unroll
  for (int r = 0; r < 16; ++r) {
    size_t idx = (size_t)(u*16 + r)*NF + m;
    run += bf2f(kfb[idx]);
    qfb[idx] = f2bf(bf2f(qfb[idx]) / run);
  }
}

// ---- V transpose -> bf16: vtb[h][e][n] ----
__global__ __launch_bounds__(256) void kv_t(const float* __restrict__ v,
                                            unsigned short* __restrict__ vtb) {
  const int h = blockIdx.y, n0 = blockIdx.x*64;
  __shared__ float t[64][65];
  const int tid = threadIdx.x;
  for (int i = tid; i < 4096; i += 256) {
    int n = i >> 6, e = i & 63;
    t[n][e] = v[((size_t)h*SEQ + n0 + n)*DH + e];
  }
  __syncthreads();
  for (int i = tid; i < 4096; i += 256) {
    int e = i >> 6, n = i & 63;
    vtb[((size_t)h*DH + e)*SEQ + n0 + n] = f2bf(t[n][e]);
  }
}

// ---- causal attention: block = 4 row-tiles sharing LDS-staged K/V tiles ----
// job = (bt, jc): row-tiles 4bt..4bt+3, j-tiles [16jc, min(16jc+16, 4bt+4)).
// 2-phase pipeline: write staged regs -> barrier -> issue next loads -> compute.
#define JC 16
__global__ __launch_bounds__(256) void k_attn(const unsigned short* __restrict__ qpb,
                                              const unsigned short* __restrict__ kfb,
                                              const unsigned short* __restrict__ vtb,
                                              float* __restrict__ out,
                                              float* __restrict__ part) {
  const int h = blockIdx.y;
  int rjob = blockIdx.x, bt = 0, jc = 0;
  for (int b = 31; b >= 0; --b) {              // big jobs first
    int n = (b >> 2) + 1;
    if (rjob < n) { bt = b; jc = rjob; break; }
    rjob -= n;
  }
  const int wid = threadIdx.x >> 6, lane = threadIdx.x & 63;
  const int t = 4*bt + wid;
  const int lr = lane & 15, g = lane >> 4;
  const int j0 = jc * JC;
  const int jblk = (j0 + JC < 4*bt + 4) ? (j0 + JC) : (4*bt + 4);
  const int jend = (jblk < t + 1) ? jblk : (t + 1);
  const bool diag = (jc == (bt >> 2));

  __shared__ unsigned short Ks[4096];   // 16 rows x 256 feats (8KB), XOR-swizzled
  __shared__ unsigned short Vs[1024];   // 64 e x 16 n (2KB)

  // Q' A-fragments, persistent
  const unsigned short* qb = qpb + ((size_t)(h*SEQ + t*16 + lr))*NF + g*8;
  bf8 qf[8];
#pragma unroll
  for (int kb = 0; kb < 8; ++kb) qf[kb] = *(const bf8*)(qb + kb*32);

  f4 o0 = {0,0,0,0}, o1 = {0,0,0,0}, o2 = {0,0,0,0}, o3 = {0,0,0,0};

  const char* kTile = (const char*)(kfb + (size_t)h*SEQ*NF);   // tile j at +j*8192
  const char* vTile = (const char*)(vtb + (size_t)h*DH*SEQ);   // row e stride 4096B

  // per-lane staging offsets (block stages 8KB K + 2KB V per tile)
  const int ko0 = (wid*2 + 0)*1024 + lane*16;
  const int ko1 = (wid*2 + 1)*1024 + lane*16;
  const int kw0 = ko0 ^ (((ko0 >> 9) & 7) << 4);
  const int kw1 = ko1 ^ (((ko1 >> 9) & 7) << 4);
  const int vo = wid*512 + lane*8;      // V LDS byte offset
  const int ve = vo >> 5;               // e row (0..63)
  const int vn = vo & 31;               // byte within 32B n-row

  f4 sk0, sk1; u32x2 sv;
  {  // prologue: issue loads for j0
    const char* kt = kTile + (size_t)j0*8192;
    sk0 = *(const f4*)(kt + ko0);
    sk1 = *(const f4*)(kt + ko1);
    sv  = *(const u32x2*)(vTile + (size_t)ve*4096 + (size_t)j0*32 + vn);
  }

  for (int j = j0; j < jblk; ++j) {
    // write staged tile j to LDS
    *(f4*)((char*)Ks + kw0) = sk0;
    *(f4*)((char*)Ks + kw1) = sk1;
    *(u32x2*)((char*)Vs + vo) = sv;
    __syncthreads();
    // issue loads for tile j+1 (fly under compute)
    if (j + 1 < jblk) {
      const char* kt = kTile + (size_t)(j+1)*8192;
      sk0 = *(const f4*)(kt + ko0);
      sk1 = *(const f4*)(kt + ko1);
      sv  = *(const u32x2*)(vTile + (size_t)ve*4096 + (size_t)(j+1)*32 + vn);
    }
    if (j < jend) {
      bf8 kcs[8];
#pragma unroll
      for (int kb = 0; kb < 8; ++kb) {
        int off = (lr*512 + kb*64 + g*16) ^ ((lr & 7) << 4);
        kcs[kb] = *(const bf8*)((const char*)Ks + off);
      }
      f4 st = {0,0,0,0};
#pragma unroll
      for (int kb = 0; kb < 8; ++kb)
        st = __builtin_amdgcn_mfma_f32_16x16x32_bf16(kcs[kb], qf[kb], st, 0, 0, 0);
      if (j == t) {
#pragma unroll
        for (int rr = 0; rr < 4; ++rr) if (g*4 + rr > lr) st[rr] = 0.f;
      }
      bf8 sb = { (short)f2bf(st[0]), (short)f2bf(st[1]), (short)f2bf(st[2]), (short)f2bf(st[3]),
                 (short)0, (short)0, (short)0, (short)0 };
#pragma unroll
      for (int eb = 0; eb < 4; ++eb) {
        bf4 v4 = *(const bf4*)((const char*)Vs + (eb*16 + lr)*32 + g*8);
        bf8 vf = { v4[0], v4[1], v4[2], v4[3], (short)0, (short)0, (short)0, (short)0 };
        f4 acc = (eb == 0) ? o0 : (eb == 1) ? o1 : (eb == 2) ? o2 : o3;
        acc = __builtin_amdgcn_mfma_f32_16x16x32_bf16(sb, vf, acc, 0, 0, 0);
        if (eb == 0) o0 = acc; else if (eb == 1) o1 = acc; else if (eb == 2) o2 = acc; else o3 = acc;
      }
    }
    __syncthreads();
  }

  float* ob;
  if (diag) {
    ob = out + ((size_t)(h*SEQ + t*16))*DH;
  } else {
    const int a = t >> 4;
    const int pS = 8*a*(a-1) + a*(t & 15);     // sum_{s<t} floor(s/16)
    ob = part + ((size_t)(h*448 + pS + jc))*1024;
  }
#pragma unroll
  for (int rr = 0; rr < 4; ++rr) {
    ob[(size_t)(4*g + rr)*DH +  0 + lr] = o0[rr];
    ob[(size_t)(4*g + rr)*DH + 16 + lr] = o1[rr];
    ob[(size_t)(4*g + rr)*DH + 32 + lr] = o2[rr];
    ob[(size_t)(4*g + rr)*DH + 48 + lr] = o3[rr];
  }
}

// ---- add partial chunks into out ----
__global__ __launch_bounds__(256) void k_red(float* __restrict__ out,
                                             const float* __restrict__ part) {
  const int idx = blockIdx.x*256 + threadIdx.x;   // 524288
  const int e = idx & 63, row = idx >> 6;
  const int h = row >> 11, n = row & 2047;
  const int t = n >> 4, lr = n & 15;
  const int a = t >> 4;                 // number of partial chunks
  if (a == 0) return;
  const int pS = 8*a*(a-1) + a*(t & 15);
  float s = out[idx];
  for (int c = 0; c < a; ++c)
    s += part[((size_t)(h*448 + pS + c))*1024 + (size_t)lr*64 + e];
  out[idx] = s;
}

extern "C" void kernel_launch(void* const* d_in, const int* in_sizes, int n_in,
                              void* d_out, int out_size, void* d_ws, size_t ws_size,
                              hipStream_t stream) {
  const float* q = (const float*)d_in[0];
  const float* k = (const float*)d_in[1];
  const float* v = (const float*)d_in[2];
  const float* P = (const float*)d_in[3];
  float* out = (float*)d_out;

  char* ws = (char*)d_ws;
  unsigned short* qfb = (unsigned short*)(ws);              // 4 MB
  unsigned short* kfb = (unsigned short*)(ws + 4194304);    // 4 MB
  unsigned short* vtb = (unsigned short*)(ws + 8388608);    // 1 MB
  // attn-phase region [9437184, 16777216): partials 4*448*4KB = 7.34 MB (exact)
  float* part  = (float*)(ws + 9437184);
  // feature-phase overlays (dead before k_attn):
  float* bmax  = (float*)(ws + 9437184);                    // 32 KB
  float* gmaxp = (float*)(ws + 9469952);                    // 256 B
  float* csum  = (float*)(ws + 9470208);                    // 512 KB
  unsigned short* phi = (unsigned short*)(ws + 9994496);    // 32 KB
  unsigned short* plo = (unsigned short*)(ws + 10027264);   // 32 KB

  fp_prep <<<64, 256, 0, stream>>>(P, phi, plo);
  k_projQK<<<256, 256, 0, stream>>>(q, k, phi, plo, qfb, bmax);
  kk_gmax <<<1, 256, 0, stream>>>(bmax, gmaxp);
  k_projKF<<<128, 256, 0, stream>>>(k, phi, plo, gmaxp, kfb, csum);
  k_scan  <<<4, 256, 0, stream>>>(csum);
  k_prime <<<512, 256, 0, stream>>>(qfb, kfb, csum);
  kv_t    <<<dim3(SEQ/64, NH), 256, 0, stream>>>(v, vtb);
  k_attn  <<<dim3(144, NH), 256, 0, stream>>>(qfb, kfb, vtb, out, part);
  k_red   <<<2048, 256, 0, stream>>>(out, part);
}

// Round 5
// 71.540 us; speedup vs baseline: 12.8755x; 1.2093x over previous
//
#include <hip/hip_runtime.h>
#include <math.h>

// Problem constants (B=1, H=4, N=2048, D=64, M=256)
#define NH   4
#define SEQ  2048
#define DH   64
#define NF   256
#define ROWS (NH*SEQ)                // 8192
#define DN    0.35355339059327373f   // 64^-0.25
#define DIAGC 0.0625f                // 0.5*DN*DN
#define RATIO 0.0625f                // 1/sqrt(256)
#define EPSF  1e-4f

typedef __attribute__((ext_vector_type(8))) short bf8;
typedef __attribute__((ext_vector_type(4))) short bf4;
typedef __attribute__((ext_vector_type(4))) float f4;
typedef __attribute__((ext_vector_type(2))) unsigned int u32x2;

static __device__ __forceinline__ unsigned short f2bf(float x) {
  union { float f; unsigned u; } v; v.f = x;
  unsigned r = v.u + 0x7FFF + ((v.u >> 16) & 1);
  return (unsigned short)(r >> 16);
}
static __device__ __forceinline__ float bf2f(unsigned short b) {
  union { unsigned u; float f; } v; v.u = ((unsigned)b) << 16;
  return v.f;
}

// ---------------- P -> bf16 hi/lo split ----------------
__global__ __launch_bounds__(256) void fp_prep(const float* __restrict__ P,
                                               unsigned short* __restrict__ phi,
                                               unsigned short* __restrict__ plo) {
  int i = blockIdx.x*256 + threadIdx.x;   // < 16384
  float p = P[i];
  unsigned short h = f2bf(p);
  phi[i] = h;
  plo[i] = f2bf(p - bf2f(h));
}

// ---- fused projection (q: full features; k: dsh-diag fp32 + rowmax) + V^T ----
// blocks 0..511: q tiles; 512..1023: k tiles; 1024..1151: V transpose.
// proj block = one 16-row tile, 4 waves x 4 feature-col-tiles (ct) each.
__global__ __launch_bounds__(256) void k_proj(const float* __restrict__ q,
    const float* __restrict__ k, const float* __restrict__ v,
    const unsigned short* __restrict__ phi, const unsigned short* __restrict__ plo,
    unsigned short* __restrict__ qfb, float* __restrict__ dshd,
    float* __restrict__ bmax, unsigned short* __restrict__ vtb) {
  __shared__ float lds[64*65];
  const int b = blockIdx.x;
  if (b >= 1024) {                       // ---- V transpose: 128 blocks, 64 rows ----
    const int cb = b - 1024;             // 0..127
    const int h = cb >> 5, n0 = (cb & 31) * 64;
    const int tid = threadIdx.x;
    for (int i = tid; i < 4096; i += 256) {
      int n = i >> 6, e = i & 63;
      lds[n*65 + e] = v[((size_t)h*SEQ + n0 + n)*DH + e];
    }
    __syncthreads();
    for (int i = tid; i < 4096; i += 256) {
      int e = i >> 6, n = i & 63;
      vtb[((size_t)h*DH + e)*SEQ + n0 + n] = f2bf(lds[n*65 + e]);
    }
    return;
  }
  const bool isq = b < 512;
  const int tile = isq ? b : b - 512;    // h*128 + t
  const int w = threadIdx.x >> 6, lane = threadIdx.x & 63;
  const int lr = lane & 15, g = lane >> 4;
  const float* x = (isq ? q : k) + (size_t)tile*16*DH;

  // x A-fragment for row lr: cols [g*8,g*8+8) and [32+g*8,32+g*8+8)
  f4 a  = *(const f4*)(x + lr*DH + g*8);
  f4 bb = *(const f4*)(x + lr*DH + g*8 + 4);
  f4 c  = *(const f4*)(x + lr*DH + 32 + g*8);
  f4 d  = *(const f4*)(x + lr*DH + 32 + g*8 + 4);
  float ss = 0.f;
#pragma unroll
  for (int i = 0; i < 4; ++i) ss += a[i]*a[i] + bb[i]*bb[i] + c[i]*c[i] + d[i]*d[i];
  ss += __shfl_xor(ss, 16);
  ss += __shfl_xor(ss, 32);              // full sum(x^2) of row lr, all lanes

  bf8 xh0, xh1, xl0, xl1;
#pragma unroll
  for (int i = 0; i < 4; ++i) {
    float v0 = DN*a[i], v1 = DN*bb[i], v2 = DN*c[i], v3 = DN*d[i];
    unsigned short h0 = f2bf(v0), h1 = f2bf(v1), h2 = f2bf(v2), h3 = f2bf(v3);
    xh0[i] = (short)h0; xh0[i+4] = (short)h1;
    xh1[i] = (short)h2; xh1[i+4] = (short)h3;
    xl0[i]   = (short)f2bf(v0 - bf2f(h0)); xl0[i+4] = (short)f2bf(v1 - bf2f(h1));
    xl1[i]   = (short)f2bf(v2 - bf2f(h2)); xl1[i+4] = (short)f2bf(v3 - bf2f(h3));
  }

  const int ct0 = w*4;
  f4 dsh[4];
#pragma unroll
  for (int cc = 0; cc < 4; ++cc) {
    const int ct = ct0 + cc;
    const unsigned short* pr = phi + (ct*16 + lr)*DH + g*8;
    const unsigned short* pl = plo + (ct*16 + lr)*DH + g*8;
    bf8 bh0 = *(const bf8*)(pr);
    bf8 bh1 = *(const bf8*)(pr + 32);
    bf8 bl0 = *(const bf8*)(pl);
    bf8 bl1 = *(const bf8*)(pl + 32);
    f4 acc = {0.f, 0.f, 0.f, 0.f};
    acc = __builtin_amdgcn_mfma_f32_16x16x32_bf16(xh0, bh0, acc, 0, 0, 0);
    acc = __builtin_amdgcn_mfma_f32_16x16x32_bf16(xh1, bh1, acc, 0, 0, 0);
    acc = __builtin_amdgcn_mfma_f32_16x16x32_bf16(xh0, bl0, acc, 0, 0, 0);
    acc = __builtin_amdgcn_mfma_f32_16x16x32_bf16(xh1, bl1, acc, 0, 0, 0);
    acc = __builtin_amdgcn_mfma_f32_16x16x32_bf16(xl0, bh0, acc, 0, 0, 0);
    acc = __builtin_amdgcn_mfma_f32_16x16x32_bf16(xl1, bh1, acc, 0, 0, 0);
    dsh[cc] = acc;
  }

  // per-row max over this wave's 4 cts, then across lanes, then across waves
  f4 mr;
#pragma unroll
  for (int r = 0; r < 4; ++r)
    mr[r] = fmaxf(fmaxf(dsh[0][r], dsh[1][r]), fmaxf(dsh[2][r], dsh[3][r]));
#pragma unroll
  for (int mk = 1; mk <= 8; mk <<= 1) {
#pragma unroll
    for (int r = 0; r < 4; ++r) mr[r] = fmaxf(mr[r], __shfl_xor(mr[r], mk));
  }
  if (lr == 0) {
#pragma unroll
    for (int r = 0; r < 4; ++r) lds[w*16 + 4*g + r] = mr[r];
  }
  __syncthreads();
  float rm[4], sr[4];
#pragma unroll
  for (int r = 0; r < 4; ++r) {
    rm[r] = fmaxf(fmaxf(lds[0*16 + 4*g + r], lds[1*16 + 4*g + r]),
                  fmaxf(lds[2*16 + 4*g + r], lds[3*16 + 4*g + r]));
    sr[r] = __shfl(ss, 4*g + r);
  }

  if (isq) {
    unsigned short* ob = qfb + (size_t)tile*16*NF;
#pragma unroll
    for (int cc = 0; cc < 4; ++cc) {
#pragma unroll
      for (int r = 0; r < 4; ++r)
        ob[(4*g + r)*NF + (ct0 + cc)*16 + lr] =
            f2bf(RATIO*(expf(dsh[cc][r] - (sr[r]*DIAGC + rm[r])) + EPSF));
    }
  } else {
    float* db = dshd + (size_t)tile*16*NF;
#pragma unroll
    for (int cc = 0; cc < 4; ++cc) {
#pragma unroll
      for (int r = 0; r < 4; ++r)
        db[(4*g + r)*NF + (ct0 + cc)*16 + lr] = dsh[cc][r] - sr[r]*DIAGC;
    }
    if (w == 0 && lr == 0) {
#pragma unroll
      for (int r = 0; r < 4; ++r) bmax[tile*16 + 4*g + r] = rm[r];
    }
  }
}

__global__ __launch_bounds__(256) void kk_gmax(const float* __restrict__ bmax,
                                               float* __restrict__ gmaxp) {
  __shared__ float red[256];
  const int t = threadIdx.x;
  float mx = -3.4e38f;
  for (int i = t; i < ROWS; i += 256) mx = fmaxf(mx, bmax[i]);
  red[t] = mx;
  __syncthreads();
  for (int s = 128; s > 0; s >>= 1) {
    if (t < s) red[t] = fmaxf(red[t], red[t+s]);
    __syncthreads();
  }
  if (t == 0) gmaxp[0] = red[0];
}

// ---- k_feat: exp(dshd - g) -> bf16 + per-tile feature sums ----
__global__ __launch_bounds__(256) void k_feat2(const float* __restrict__ dshd,
    const float* __restrict__ gmaxp, unsigned short* __restrict__ kfb,
    float* __restrict__ csum) {
  const int u = blockIdx.x, m = threadIdx.x;     // u: 0..511 = h*128 + t
  const float gg = gmaxp[0];
  const float* db = dshd + (size_t)u*16*NF + m;
  unsigned short* ob = kfb + (size_t)u*16*NF + m;
  float run = 0.f;
#pragma unroll
  for (int r = 0; r < 16; ++r) {
    unsigned short bv = f2bf(RATIO*(expf(db[r*NF] - gg) + EPSF));
    ob[r*NF] = bv;
    run += bf2f(bv);
  }
  csum[(size_t)u*NF + m] = run;
}

// ---- q' = q_feat / cumsum(k_feat): prefix walk + in-place divide ----
__global__ __launch_bounds__(256) void k_prime2(unsigned short* __restrict__ qfb,
    const unsigned short* __restrict__ kfb, const float* __restrict__ csum) {
  const int u = blockIdx.x, m = threadIdx.x;     // u = h*128 + t
  const int h = u >> 7, t = u & 127;
  const float* cs = csum + (size_t)(h*128)*NF + m;
  float run = 0.f;
#pragma unroll 8
  for (int c = 0; c < t; ++c) run += cs[(size_t)c*NF];
#pragma unroll
  for (int r = 0; r < 16; ++r) {
    size_t idx = (size_t)(u*16 + r)*NF + m;
    run += bf2f(kfb[idx]);
    qfb[idx] = f2bf(bf2f(qfb[idx]) / run);
  }
}

// ---- causal attention: block = 4 row-tiles sharing LDS-staged K/V tiles ----
#define JC 16
__global__ __launch_bounds__(256) void k_attn(const unsigned short* __restrict__ qpb,
                                              const unsigned short* __restrict__ kfb,
                                              const unsigned short* __restrict__ vtb,
                                              float* __restrict__ out,
                                              float* __restrict__ part) {
  const int h = blockIdx.y;
  int rjob = blockIdx.x, bt = 0, jc = 0;
  for (int b = 31; b >= 0; --b) {              // big jobs first
    int n = (b >> 2) + 1;
    if (rjob < n) { bt = b; jc = rjob; break; }
    rjob -= n;
  }
  const int wid = threadIdx.x >> 6, lane = threadIdx.x & 63;
  const int t = 4*bt + wid;
  const int lr = lane & 15, g = lane >> 4;
  const int j0 = jc * JC;
  const int jblk = (j0 + JC < 4*bt + 4) ? (j0 + JC) : (4*bt + 4);
  const int jend = (jblk < t + 1) ? jblk : (t + 1);
  const bool diag = (jc == (bt >> 2));

  __shared__ unsigned short Ks[4096];   // 16 rows x 256 feats (8KB), XOR-swizzled
  __shared__ unsigned short Vs[1024];   // 64 e x 16 n (2KB)

  const unsigned short* qb = qpb + ((size_t)(h*SEQ + t*16 + lr))*NF + g*8;
  bf8 qf[8];
#pragma unroll
  for (int kb = 0; kb < 8; ++kb) qf[kb] = *(const bf8*)(qb + kb*32);

  f4 o0 = {0,0,0,0}, o1 = {0,0,0,0}, o2 = {0,0,0,0}, o3 = {0,0,0,0};

  const char* kTile = (const char*)(kfb + (size_t)h*SEQ*NF);   // tile j at +j*8192
  const char* vTile = (const char*)(vtb + (size_t)h*DH*SEQ);   // e row stride 4096B

  const int ko0 = (wid*2 + 0)*1024 + lane*16;
  const int ko1 = (wid*2 + 1)*1024 + lane*16;
  const int kw0 = ko0 ^ (((ko0 >> 9) & 7) << 4);
  const int kw1 = ko1 ^ (((ko1 >> 9) & 7) << 4);
  const int vo = wid*512 + lane*8;
  const int ve = vo >> 5;
  const int vn = vo & 31;

  f4 sk0, sk1; u32x2 sv;
  {
    const char* kt = kTile + (size_t)j0*8192;
    sk0 = *(const f4*)(kt + ko0);
    sk1 = *(const f4*)(kt + ko1);
    sv  = *(const u32x2*)(vTile + (size_t)ve*4096 + (size_t)j0*32 + vn);
  }

  for (int j = j0; j < jblk; ++j) {
    *(f4*)((char*)Ks + kw0) = sk0;
    *(f4*)((char*)Ks + kw1) = sk1;
    *(u32x2*)((char*)Vs + vo) = sv;
    __syncthreads();
    if (j + 1 < jblk) {
      const char* kt = kTile + (size_t)(j+1)*8192;
      sk0 = *(const f4*)(kt + ko0);
      sk1 = *(const f4*)(kt + ko1);
      sv  = *(const u32x2*)(vTile + (size_t)ve*4096 + (size_t)(j+1)*32 + vn);
    }
    if (j < jend) {
      bf8 kcs[8];
#pragma unroll
      for (int kb = 0; kb < 8; ++kb) {
        int off = (lr*512 + kb*64 + g*16) ^ ((lr & 7) << 4);
        kcs[kb] = *(const bf8*)((const char*)Ks + off);
      }
      f4 st = {0,0,0,0};
#pragma unroll
      for (int kb = 0; kb < 8; ++kb)
        st = __builtin_amdgcn_mfma_f32_16x16x32_bf16(kcs[kb], qf[kb], st, 0, 0, 0);
      if (j == t) {
#pragma unroll
        for (int rr = 0; rr < 4; ++rr) if (g*4 + rr > lr) st[rr] = 0.f;
      }
      bf8 sb = { (short)f2bf(st[0]), (short)f2bf(st[1]), (short)f2bf(st[2]), (short)f2bf(st[3]),
                 (short)0, (short)0, (short)0, (short)0 };
#pragma unroll
      for (int eb = 0; eb < 4; ++eb) {
        bf4 v4 = *(const bf4*)((const char*)Vs + (eb*16 + lr)*32 + g*8);
        bf8 vf = { v4[0], v4[1], v4[2], v4[3], (short)0, (short)0, (short)0, (short)0 };
        f4 acc = (eb == 0) ? o0 : (eb == 1) ? o1 : (eb == 2) ? o2 : o3;
        acc = __builtin_amdgcn_mfma_f32_16x16x32_bf16(sb, vf, acc, 0, 0, 0);
        if (eb == 0) o0 = acc; else if (eb == 1) o1 = acc; else if (eb == 2) o2 = acc; else o3 = acc;
      }
    }
    __syncthreads();
  }

  float* ob;
  if (diag) {
    ob = out + ((size_t)(h*SEQ + t*16))*DH;
  } else {
    const int a = t >> 4;
    const int pS = 8*a*(a-1) + a*(t & 15);     // sum_{s<t} floor(s/16)
    ob = part + ((size_t)(h*448 + pS + jc))*1024;
  }
#pragma unroll
  for (int rr = 0; rr < 4; ++rr) {
    ob[(size_t)(4*g + rr)*DH +  0 + lr] = o0[rr];
    ob[(size_t)(4*g + rr)*DH + 16 + lr] = o1[rr];
    ob[(size_t)(4*g + rr)*DH + 32 + lr] = o2[rr];
    ob[(size_t)(4*g + rr)*DH + 48 + lr] = o3[rr];
  }
}

// ---- add partial chunks into out ----
__global__ __launch_bounds__(256) void k_red(float* __restrict__ out,
                                             const float* __restrict__ part) {
  const int idx = blockIdx.x*256 + threadIdx.x;   // 524288
  const int e = idx & 63, row = idx >> 6;
  const int h = row >> 11, n = row & 2047;
  const int t = n >> 4, lr = n & 15;
  const int a = t >> 4;
  if (a == 0) return;
  const int pS = 8*a*(a-1) + a*(t & 15);
  float s = out[idx];
  for (int c = 0; c < a; ++c)
    s += part[((size_t)(h*448 + pS + c))*1024 + (size_t)lr*64 + e];
  out[idx] = s;
}

extern "C" void kernel_launch(void* const* d_in, const int* in_sizes, int n_in,
                              void* d_out, int out_size, void* d_ws, size_t ws_size,
                              hipStream_t stream) {
  const float* q = (const float*)d_in[0];
  const float* k = (const float*)d_in[1];
  const float* v = (const float*)d_in[2];
  const float* P = (const float*)d_in[3];
  float* out = (float*)d_out;

  char* ws = (char*)d_ws;                                   // 256 MiB available
  unsigned short* qfb = (unsigned short*)(ws);              // 4 MB
  unsigned short* kfb = (unsigned short*)(ws + (4u<<20));   // 4 MB
  unsigned short* vtb = (unsigned short*)(ws + (8u<<20));   // 1 MB
  float* dshd  = (float*)(ws + (16u<<20));                  // 8 MB
  float* part  = (float*)(ws + (32u<<20));                  // 7.34 MB
  float* bmax  = (float*)(ws + (40u<<20));                  // 32 KB
  float* gmaxp = (float*)(ws + (40u<<20) + 32768);          // 4 B
  float* csum  = (float*)(ws + (41u<<20));                  // 512 KB
  unsigned short* phi = (unsigned short*)(ws + (42u<<20));          // 32 KB
  unsigned short* plo = (unsigned short*)(ws + (42u<<20) + 32768);  // 32 KB

  fp_prep <<<64, 256, 0, stream>>>(P, phi, plo);
  k_proj  <<<1152, 256, 0, stream>>>(q, k, v, phi, plo, qfb, dshd, bmax, vtb);
  kk_gmax <<<1, 256, 0, stream>>>(bmax, gmaxp);
  k_feat2 <<<512, 256, 0, stream>>>(dshd, gmaxp, kfb, csum);
  k_prime2<<<512, 256, 0, stream>>>(qfb, kfb, csum);
  k_attn  <<<dim3(144, NH), 256, 0, stream>>>(qfb, kfb, vtb, out, part);
  k_red   <<<2048, 256, 0, stream>>>(out, part);
}

// Round 7
// 66.544 us; speedup vs baseline: 13.8422x; 1.0751x over previous
//
#include <hip/hip_runtime.h>
#include <math.h>

// Problem constants (B=1, H=4, N=2048, D=64, M=256)
#define NH   4
#define SEQ  2048
#define DH   64
#define NF   256
#define ROWS (NH*SEQ)                // 8192
#define DN    0.35355339059327373f   // 64^-0.25
#define DIAGC 0.0625f                // 0.5*DN*DN
#define RATIO 0.0625f                // 1/sqrt(256)
#define EPSF  1e-4f

typedef __attribute__((ext_vector_type(8))) short bf8;
typedef __attribute__((ext_vector_type(4))) short bf4;
typedef __attribute__((ext_vector_type(4))) float f4;
typedef __attribute__((ext_vector_type(2))) unsigned int u32x2;

static __device__ __forceinline__ unsigned short f2bf(float x) {
  union { float f; unsigned u; } v; v.f = x;
  unsigned r = v.u + 0x7FFF + ((v.u >> 16) & 1);
  return (unsigned short)(r >> 16);
}
static __device__ __forceinline__ float bf2f(unsigned short b) {
  union { unsigned u; float f; } v; v.u = ((unsigned)b) << 16;
  return v.f;
}

// ---- fused projection (q: full features; k: dsh-diag fp32 + rowmax) + V^T ----
// blocks 0..511: q tiles; 512..1023: k tiles; 1024..1151: V transpose.
__global__ __launch_bounds__(256) void k_proj(const float* __restrict__ q,
    const float* __restrict__ k, const float* __restrict__ v,
    const float* __restrict__ P,
    unsigned short* __restrict__ qfb, float* __restrict__ dshd,
    float* __restrict__ bmax, unsigned short* __restrict__ vtb) {
  __shared__ float lds[64*65];
  const int b = blockIdx.x;
  if (b >= 1024) {                       // ---- V transpose: 128 blocks ----
    const int cb = b - 1024;
    const int h = cb >> 5, n0 = (cb & 31) * 64;
    const int tid = threadIdx.x;
    for (int i = tid; i < 4096; i += 256) {
      int n = i >> 6, e = i & 63;
      lds[n*65 + e] = v[((size_t)h*SEQ + n0 + n)*DH + e];
    }
    __syncthreads();
    for (int i = tid; i < 4096; i += 256) {
      int e = i >> 6, n = i & 63;
      vtb[((size_t)h*DH + e)*SEQ + n0 + n] = f2bf(lds[n*65 + e]);
    }
    return;
  }
  const bool isq = b < 512;
  const int tile = isq ? b : b - 512;    // h*128 + t
  const int w = threadIdx.x >> 6, lane = threadIdx.x & 63;
  const int lr = lane & 15, g = lane >> 4;
  const float* x = (isq ? q : k) + (size_t)tile*16*DH;

  f4 a  = *(const f4*)(x + lr*DH + g*8);
  f4 bb = *(const f4*)(x + lr*DH + g*8 + 4);
  f4 c  = *(const f4*)(x + lr*DH + 32 + g*8);
  f4 d  = *(const f4*)(x + lr*DH + 32 + g*8 + 4);
  float ss = 0.f;
#pragma unroll
  for (int i = 0; i < 4; ++i) ss += a[i]*a[i] + bb[i]*bb[i] + c[i]*c[i] + d[i]*d[i];
  ss += __shfl_xor(ss, 16);
  ss += __shfl_xor(ss, 32);              // full sum(x^2) of row lr

  bf8 xh0, xh1, xl0, xl1;
#pragma unroll
  for (int i = 0; i < 4; ++i) {
    float v0 = DN*a[i], v1 = DN*bb[i], v2 = DN*c[i], v3 = DN*d[i];
    unsigned short h0 = f2bf(v0), h1 = f2bf(v1), h2 = f2bf(v2), h3 = f2bf(v3);
    xh0[i] = (short)h0; xh0[i+4] = (short)h1;
    xh1[i] = (short)h2; xh1[i+4] = (short)h3;
    xl0[i]   = (short)f2bf(v0 - bf2f(h0)); xl0[i+4] = (short)f2bf(v1 - bf2f(h1));
    xl1[i]   = (short)f2bf(v2 - bf2f(h2)); xl1[i+4] = (short)f2bf(v3 - bf2f(h3));
  }

  const int ct0 = w*4;
  f4 dsh[4];
#pragma unroll
  for (int cc = 0; cc < 4; ++cc) {
    const int ct = ct0 + cc;
    const float* prow = P + (ct*16 + lr)*DH + g*8;
    f4 p0 = *(const f4*)(prow);
    f4 p1 = *(const f4*)(prow + 4);
    f4 p2 = *(const f4*)(prow + 32);
    f4 p3 = *(const f4*)(prow + 36);
    bf8 bh0, bl0, bh1, bl1;
#pragma unroll
    for (int i = 0; i < 4; ++i) {
      unsigned short h0 = f2bf(p0[i]), h1 = f2bf(p1[i]);
      unsigned short h2 = f2bf(p2[i]), h3 = f2bf(p3[i]);
      bh0[i] = (short)h0; bh0[i+4] = (short)h1;
      bh1[i] = (short)h2; bh1[i+4] = (short)h3;
      bl0[i]   = (short)f2bf(p0[i] - bf2f(h0)); bl0[i+4] = (short)f2bf(p1[i] - bf2f(h1));
      bl1[i]   = (short)f2bf(p2[i] - bf2f(h2)); bl1[i+4] = (short)f2bf(p3[i] - bf2f(h3));
    }
    f4 acc = {0.f, 0.f, 0.f, 0.f};
    acc = __builtin_amdgcn_mfma_f32_16x16x32_bf16(xh0, bh0, acc, 0, 0, 0);
    acc = __builtin_amdgcn_mfma_f32_16x16x32_bf16(xh1, bh1, acc, 0, 0, 0);
    acc = __builtin_amdgcn_mfma_f32_16x16x32_bf16(xh0, bl0, acc, 0, 0, 0);
    acc = __builtin_amdgcn_mfma_f32_16x16x32_bf16(xh1, bl1, acc, 0, 0, 0);
    acc = __builtin_amdgcn_mfma_f32_16x16x32_bf16(xl0, bh0, acc, 0, 0, 0);
    acc = __builtin_amdgcn_mfma_f32_16x16x32_bf16(xl1, bh1, acc, 0, 0, 0);
    dsh[cc] = acc;
  }

  f4 mr;
#pragma unroll
  for (int r = 0; r < 4; ++r)
    mr[r] = fmaxf(fmaxf(dsh[0][r], dsh[1][r]), fmaxf(dsh[2][r], dsh[3][r]));
#pragma unroll
  for (int mk = 1; mk <= 8; mk <<= 1) {
#pragma unroll
    for (int r = 0; r < 4; ++r) mr[r] = fmaxf(mr[r], __shfl_xor(mr[r], mk));
  }
  if (lr == 0) {
#pragma unroll
    for (int r = 0; r < 4; ++r) lds[w*16 + 4*g + r] = mr[r];
  }
  __syncthreads();
  float rm[4], sr[4];
#pragma unroll
  for (int r = 0; r < 4; ++r) {
    rm[r] = fmaxf(fmaxf(lds[0*16 + 4*g + r], lds[1*16 + 4*g + r]),
                  fmaxf(lds[2*16 + 4*g + r], lds[3*16 + 4*g + r]));
    sr[r] = __shfl(ss, 4*g + r);
  }

  if (isq) {
    unsigned short* ob = qfb + (size_t)tile*16*NF;
#pragma unroll
    for (int cc = 0; cc < 4; ++cc) {
#pragma unroll
      for (int r = 0; r < 4; ++r)
        ob[(4*g + r)*NF + (ct0 + cc)*16 + lr] =
            f2bf(RATIO*(expf(dsh[cc][r] - (sr[r]*DIAGC + rm[r])) + EPSF));
    }
  } else {
    float* db = dshd + (size_t)tile*16*NF;
#pragma unroll
    for (int cc = 0; cc < 4; ++cc) {
#pragma unroll
      for (int r = 0; r < 4; ++r)
        db[(4*g + r)*NF + (ct0 + cc)*16 + lr] = dsh[cc][r] - sr[r]*DIAGC;
    }
    if (w == 0 && lr == 0) {
#pragma unroll
      for (int r = 0; r < 4; ++r) bmax[tile*16 + 4*g + r] = rm[r];
    }
  }
}

// ---- k_feat: gmax (inline) + exp -> kfb bf16 + kft (m-major) + tile sums ----
__global__ __launch_bounds__(256) void k_feat2(const float* __restrict__ dshd,
    const float* __restrict__ bmax, unsigned short* __restrict__ kfb,
    unsigned short* __restrict__ kft, float* __restrict__ csum) {
  const int u = blockIdx.x, m = threadIdx.x;     // u: 0..511 = h*128 + t
  const int h = u >> 7, t = u & 127;
  __shared__ float red[256];
  float mx = -3.4e38f;
  for (int i = m; i < ROWS; i += 256) mx = fmaxf(mx, bmax[i]);
  red[m] = mx;
  __syncthreads();
  for (int s = 128; s > 0; s >>= 1) {
    if (m < s) red[m] = fmaxf(red[m], red[m+s]);
    __syncthreads();
  }
  const float gg = red[0];
  const float* db = dshd + (size_t)u*16*NF + m;
  unsigned short* ob = kfb + (size_t)u*16*NF + m;
  float run = 0.f;
  bf8 k0, k1;
#pragma unroll
  for (int r = 0; r < 16; ++r) {
    unsigned short bv = f2bf(RATIO*(expf(db[r*NF] - gg) + EPSF));
    ob[r*NF] = bv;
    if (r < 8) k0[r] = (short)bv; else k1[r-8] = (short)bv;
    run += bf2f(bv);
  }
  csum[(size_t)u*NF + m] = run;
  unsigned short* kt = kft + ((size_t)(h*NF + m))*SEQ + t*16;
  *(bf8*)kt = k0;
  *(bf8*)(kt + 8) = k1;
}

// ---- per-chunk state build: stateT[e][m] = sum_{j in chunk} v[j,e]*kf[j,m] ----
__global__ __launch_bounds__(256) void k_state_build(
    const unsigned short* __restrict__ vtb, const unsigned short* __restrict__ kft,
    float* __restrict__ stateP) {
  const int c = blockIdx.x, h = blockIdx.y;      // chunk 0..15, head 0..3
  const int wid = threadIdx.x >> 6, lane = threadIdx.x & 63;
  const int lr = lane & 15, g = lane >> 4;
  f4 acc[4][4];   // [et][mt]
#pragma unroll
  for (int et = 0; et < 4; ++et)
#pragma unroll
    for (int mt = 0; mt < 4; ++mt) acc[et][mt] = (f4){0.f,0.f,0.f,0.f};

#pragma unroll
  for (int ks = 0; ks < 4; ++ks) {
    const int j0 = c*128 + ks*32 + g*8;
    bf8 xv[4], ym[4];
#pragma unroll
    for (int et = 0; et < 4; ++et)
      xv[et] = *(const bf8*)(vtb + ((size_t)(h*DH + et*16 + lr))*SEQ + j0);
#pragma unroll
    for (int mt = 0; mt < 4; ++mt)
      ym[mt] = *(const bf8*)(kft + ((size_t)(h*NF + (4*wid + mt)*16 + lr))*SEQ + j0);
#pragma unroll
    for (int et = 0; et < 4; ++et)
#pragma unroll
      for (int mt = 0; mt < 4; ++mt)
        acc[et][mt] = __builtin_amdgcn_mfma_f32_16x16x32_bf16(xv[et], ym[mt], acc[et][mt], 0, 0, 0);
  }
  float* sp = stateP + (size_t)(h*16 + c)*64*NF;
#pragma unroll
  for (int et = 0; et < 4; ++et)
#pragma unroll
    for (int mt = 0; mt < 4; ++mt)
#pragma unroll
      for (int r = 0; r < 4; ++r)
        sp[(size_t)(et*16 + 4*g + r)*NF + (4*wid + mt)*16 + lr] = acc[et][mt][r];
}

// ---- exclusive cumsum of chunk states -> hi/lo bf16 ----
__global__ __launch_bounds__(256) void k_state_scan(const float* __restrict__ stateP,
    unsigned short* __restrict__ sthi, unsigned short* __restrict__ stlo) {
  const int eg = blockIdx.x, h = blockIdx.y;     // e-group 0..15
  const int er = threadIdx.x >> 6, m0 = (threadIdx.x & 63)*4;
  const int e = eg*4 + er;
  f4 run = {0.f, 0.f, 0.f, 0.f};
  for (int c = 0; c < 16; ++c) {
    const size_t idx = (size_t)((h*16 + c)*64 + e)*NF + m0;
    unsigned short hi[4], lo[4];
#pragma unroll
    for (int i = 0; i < 4; ++i) {
      hi[i] = f2bf(run[i]);
      lo[i] = f2bf(run[i] - bf2f(hi[i]));
    }
    *(bf4*)(sthi + idx) = *(bf4*)hi;
    *(bf4*)(stlo + idx) = *(bf4*)lo;
    run += *(const f4*)(stateP + idx);
  }
}

// ---- q' = q_feat / cumsum(k_feat): prefix walk + in-place divide ----
__global__ __launch_bounds__(256) void k_prime2(unsigned short* __restrict__ qfb,
    const unsigned short* __restrict__ kfb, const float* __restrict__ csum) {
  const int u = blockIdx.x, m = threadIdx.x;     // u = h*128 + t
  const int h = u >> 7, t = u & 127;
  const float* cs = csum + (size_t)(h*128)*NF + m;
  float run = 0.f;
#pragma unroll 8
  for (int c = 0; c < t; ++c) run += cs[(size_t)c*NF];
#pragma unroll
  for (int r = 0; r < 16; ++r) {
    size_t idx = (size_t)(u*16 + r)*NF + m;
    run += bf2f(kfb[idx]);
    qfb[idx] = f2bf(bf2f(qfb[idx]) / run);
  }
}

// ---- chunked causal attention: inter via state GEMM + intra within chunk ----
// block = (h, chunk, half): 32 blocks/head; 4 waves = 4 row-tiles.
__global__ __launch_bounds__(256) void k_attn2(const unsigned short* __restrict__ qpb,
                                               const unsigned short* __restrict__ kfb,
                                               const unsigned short* __restrict__ vtb,
                                               const unsigned short* __restrict__ sthi,
                                               const unsigned short* __restrict__ stlo,
                                               float* __restrict__ out) {
  const int h = blockIdx.y;
  const int b = blockIdx.x;            // 0..31
  const int c = b >> 1, half = b & 1;  // chunk 0..15
  const int wid = threadIdx.x >> 6, lane = threadIdx.x & 63;
  const int t = c*8 + half*4 + wid;    // this wave's row-tile (0..127)
  const int lr = lane & 15, g = lane >> 4;
  const int jc0 = c*8;                 // first j-tile of the chunk
  const int nstage = half*4 + 4;       // j-tiles to stage: lower 4, upper 8

  __shared__ unsigned short Ks[4096];  // 16 rows x 256 feats, XOR-swizzled
  __shared__ unsigned short Vs[1024];  // 64 e x 16 n

  // Q' A-fragments
  const unsigned short* qb = qpb + ((size_t)(h*SEQ + t*16 + lr))*NF + g*8;
  bf8 qf[8];
#pragma unroll
  for (int kb = 0; kb < 8; ++kb) qf[kb] = *(const bf8*)(qb + kb*32);

  const char* kTile = (const char*)(kfb + (size_t)h*SEQ*NF);
  const char* vTile = (const char*)(vtb + (size_t)h*DH*SEQ);

  const int ko0 = (wid*2 + 0)*1024 + lane*16;
  const int ko1 = (wid*2 + 1)*1024 + lane*16;
  const int kw0 = ko0 ^ (((ko0 >> 9) & 7) << 4);
  const int kw1 = ko1 ^ (((ko1 >> 9) & 7) << 4);
  const int vo = wid*512 + lane*8;
  const int ve = vo >> 5;
  const int vn = vo & 31;

  f4 sk0, sk1; u32x2 sv;
  {  // prologue: issue staging loads for first j-tile (fly under inter-GEMM)
    const char* kt = kTile + (size_t)jc0*8192;
    sk0 = *(const f4*)(kt + ko0);
    sk1 = *(const f4*)(kt + ko1);
    sv  = *(const u32x2*)(vTile + (size_t)ve*4096 + (size_t)jc0*32 + vn);
  }

  // ---- inter-chunk: O = q' x cumstate (hi/lo split) ----
  f4 o0 = {0,0,0,0}, o1 = {0,0,0,0}, o2 = {0,0,0,0}, o3 = {0,0,0,0};
  {
    const unsigned short* SH = sthi + ((size_t)((h*16 + c)*64 + lr))*NF + g*8;
    const unsigned short* SL = stlo + ((size_t)((h*16 + c)*64 + lr))*NF + g*8;
#pragma unroll
    for (int ks = 0; ks < 8; ++ks) {
#pragma unroll
      for (int et = 0; et < 4; ++et) {
        bf8 bh = *(const bf8*)(SH + et*16*NF + ks*32);
        bf8 bl = *(const bf8*)(SL + et*16*NF + ks*32);
        f4 acc = (et == 0) ? o0 : (et == 1) ? o1 : (et == 2) ? o2 : o3;
        acc = __builtin_amdgcn_mfma_f32_16x16x32_bf16(qf[ks], bh, acc, 0, 0, 0);
        acc = __builtin_amdgcn_mfma_f32_16x16x32_bf16(qf[ks], bl, acc, 0, 0, 0);
        if (et == 0) o0 = acc; else if (et == 1) o1 = acc; else if (et == 2) o2 = acc; else o3 = acc;
      }
    }
  }

  // ---- intra-chunk causal sweep over staged K/V tiles ----
  for (int jj = 0; jj < nstage; ++jj) {
    const int j = jc0 + jj;
    *(f4*)((char*)Ks + kw0) = sk0;
    *(f4*)((char*)Ks + kw1) = sk1;
    *(u32x2*)((char*)Vs + vo) = sv;
    __syncthreads();
    if (jj + 1 < nstage) {
      const char* kt = kTile + (size_t)(j+1)*8192;
      sk0 = *(const f4*)(kt + ko0);
      sk1 = *(const f4*)(kt + ko1);
      sv  = *(const u32x2*)(vTile + (size_t)ve*4096 + (size_t)(j+1)*32 + vn);
    }
    if (j <= t) {
      bf8 kcs[8];
#pragma unroll
      for (int kb = 0; kb < 8; ++kb) {
        int off = (lr*512 + kb*64 + g*16) ^ ((lr & 7) << 4);
        kcs[kb] = *(const bf8*)((const char*)Ks + off);
      }
      f4 st = {0,0,0,0};
#pragma unroll
      for (int kb = 0; kb < 8; ++kb)
        st = __builtin_amdgcn_mfma_f32_16x16x32_bf16(kcs[kb], qf[kb], st, 0, 0, 0);
      if (j == t) {
#pragma unroll
        for (int rr = 0; rr < 4; ++rr) if (g*4 + rr > lr) st[rr] = 0.f;
      }
      bf8 sb = { (short)f2bf(st[0]), (short)f2bf(st[1]), (short)f2bf(st[2]), (short)f2bf(st[3]),
                 (short)0, (short)0, (short)0, (short)0 };
#pragma unroll
      for (int eb = 0; eb < 4; ++eb) {
        bf4 v4 = *(const bf4*)((const char*)Vs + (eb*16 + lr)*32 + g*8);
        bf8 vf = { v4[0], v4[1], v4[2], v4[3], (short)0, (short)0, (short)0, (short)0 };
        f4 acc = (eb == 0) ? o0 : (eb == 1) ? o1 : (eb == 2) ? o2 : o3;
        acc = __builtin_amdgcn_mfma_f32_16x16x32_bf16(sb, vf, acc, 0, 0, 0);
        if (eb == 0) o0 = acc; else if (eb == 1) o1 = acc; else if (eb == 2) o2 = acc; else o3 = acc;
      }
    }
    __syncthreads();
  }

  float* ob = out + ((size_t)(h*SEQ + t*16))*DH;
#pragma unroll
  for (int rr = 0; rr < 4; ++rr) {
    ob[(size_t)(4*g + rr)*DH +  0 + lr] = o0[rr];
    ob[(size_t)(4*g + rr)*DH + 16 + lr] = o1[rr];
    ob[(size_t)(4*g + rr)*DH + 32 + lr] = o2[rr];
    ob[(size_t)(4*g + rr)*DH + 48 + lr] = o3[rr];
  }
}

extern "C" void kernel_launch(void* const* d_in, const int* in_sizes, int n_in,
                              void* d_out, int out_size, void* d_ws, size_t ws_size,
                              hipStream_t stream) {
  const float* q = (const float*)d_in[0];
  const float* k = (const float*)d_in[1];
  const float* v = (const float*)d_in[2];
  const float* P = (const float*)d_in[3];
  float* out = (float*)d_out;

  char* ws = (char*)d_ws;                                    // 256 MiB available
  unsigned short* qfb  = (unsigned short*)(ws);              // 4 MB
  unsigned short* kfb  = (unsigned short*)(ws + (4u<<20));   // 4 MB
  unsigned short* vtb  = (unsigned short*)(ws + (8u<<20));   // 1 MB
  unsigned short* kft  = (unsigned short*)(ws + (12u<<20));  // 4 MB (m-major kf)
  float* dshd   = (float*)(ws + (16u<<20));                  // 8 MB
  float* bmax   = (float*)(ws + (24u<<20));                  // 32 KB
  float* csum   = (float*)(ws + (25u<<20));                  // 512 KB
  float* stateP = (float*)(ws + (28u<<20));                  // 4 MB
  unsigned short* sthi = (unsigned short*)(ws + (33u<<20));  // 2 MB
  unsigned short* stlo = (unsigned short*)(ws + (36u<<20));  // 2 MB

  k_proj       <<<1152, 256, 0, stream>>>(q, k, v, P, qfb, dshd, bmax, vtb);
  k_feat2      <<<512, 256, 0, stream>>>(dshd, bmax, kfb, kft, csum);
  k_state_build<<<dim3(16, NH), 256, 0, stream>>>(vtb, kft, stateP);
  k_state_scan <<<dim3(16, NH), 256, 0, stream>>>(stateP, sthi, stlo);
  k_prime2     <<<512, 256, 0, stream>>>(qfb, kfb, csum);
  k_attn2      <<<dim3(32, NH), 256, 0, stream>>>(qfb, kfb, vtb, sthi, stlo, out);
}